// Round 1
// baseline (1962.682 us; speedup 1.0000x reference)
//
#include <hip/hip_runtime.h>
#include <math.h>

// ---------------------------------------------------------------------------
// Swin-3D cross-attention block, fp32 correctness-first baseline.
// B=2, C=96, D=40, H=48, W=40, window (5,6,5) -> 1024 windows x 150 tokens.
// Token order everywhere = window-partitioned order:
//   win = ((b*8 + d/5)*8 + h/6)*8 + w/5 ; t = ((d%5)*6 + h%6)*5 + w%5
//   tok = win*150 + t
// Workspace layout (U = 153600*96 floats = 59MB):
//   u0: xln  -> k   (k overwrites xln after q-proj consumed it)
//   u1: yln
//   u2: q -> x2 -> x3 (in-place; per-token ownership is block-exclusive)
//   u3: v
// Total ws = 4U floats = 236 MB.
// ---------------------------------------------------------------------------

static constexpr int NTOK = 153600;
static constexpr float SCALE = 0.10206207261596575f; // 96^-0.5

__device__ __forceinline__ int tok_index(int b, int d, int h, int w) {
    int d0 = d / 5, wd = d % 5;
    int h0 = h / 6, wh = h % 6;
    int w0 = w / 5, ww = w % 5;
    int win = ((b * 8 + d0) * 8 + h0) * 8 + w0;
    return win * 150 + (wd * 6 + wh) * 5 + ww;
}

// ---------------------------------------------------------------------------
// K1: transpose (B,C,D,H,W)->window-token order + LayerNorm for both inputs.
// grid = B*D*H = 3840 blocks, 256 threads. One (b,d,h) row of 40 w-positions.
// ---------------------------------------------------------------------------
__global__ __launch_bounds__(256) void k_ln_transpose(
    const float* __restrict__ Im, const float* __restrict__ If,
    const float* __restrict__ g1q, const float* __restrict__ b1q,
    const float* __restrict__ g1k, const float* __restrict__ b1k,
    float* __restrict__ xln, float* __restrict__ yln)
{
    __shared__ float tile[40 * 97];
    __shared__ float mean_s[40], rstd_s[40];
    int blk = blockIdx.x;
    int b = blk / (40 * 48);
    int rem = blk % (40 * 48);
    int d = rem / 48, h = rem % 48;
    int tid = threadIdx.x;

    for (int pass = 0; pass < 2; ++pass) {
        const float* src = pass ? If : Im;
        const float* gg = pass ? g1k : g1q;
        const float* bb = pass ? b1k : b1q;
        float* dst = pass ? yln : xln;

        for (int i = tid; i < 96 * 40; i += 256) {
            int c = i / 40, w = i % 40;
            tile[w * 97 + c] = src[(size_t)(b * 96 + c) * 76800 + d * 1920 + h * 40 + w];
        }
        __syncthreads();
        if (tid < 40) {
            float s = 0.f, s2 = 0.f;
            for (int c = 0; c < 96; ++c) {
                float v = tile[tid * 97 + c];
                s += v; s2 += v * v;
            }
            float m = s * (1.f / 96.f);
            float var = s2 * (1.f / 96.f) - m * m;
            mean_s[tid] = m;
            rstd_s[tid] = rsqrtf(var + 1e-5f);
        }
        __syncthreads();
        for (int i = tid; i < 40 * 96; i += 256) {
            int w = i / 96, c = i % 96;
            int tok = tok_index(b, d, h, w);
            float v = (tile[w * 97 + c] - mean_s[w]) * rstd_s[w] * gg[c] + bb[c];
            dst[(size_t)tok * 96 + c] = v;
        }
        __syncthreads();
    }
}

// ---------------------------------------------------------------------------
// K2: out[t][n] = X[t][:96] @ Wm[:96][nch+n] + bias. X in window-token order.
// N = 96 (q) or 192 (kv, split into outA[n<96]=k, outB=v).
// grid = 2400 (64 tokens/block), 256 threads, thread tile 4 tokens x 6 n.
// ---------------------------------------------------------------------------
__global__ __launch_bounds__(256) void k_gemm_proj(
    const float* __restrict__ X, const float* __restrict__ Wm,
    const float* __restrict__ bias, int N, float* outA, float* outB)
{
    __shared__ float xt[64 * 97];
    __shared__ float wt[96 * 96];
    int t0 = blockIdx.x * 64;
    int tid = threadIdx.x;

    for (int i = tid; i < 64 * 96; i += 256) {
        int t = i / 96, c = i % 96;
        xt[t * 97 + c] = X[(size_t)(t0 + t) * 96 + c];
    }
    int ty = tid >> 4, tx = tid & 15;

    for (int nch = 0; nch < N; nch += 96) {
        __syncthreads();
        for (int i = tid; i < 96 * 96; i += 256) {
            int kk = i / 96, n = i % 96;
            wt[i] = Wm[kk * N + nch + n];
        }
        __syncthreads();
        float acc[4][6] = {};
#pragma unroll 4
        for (int kk = 0; kk < 96; ++kk) {
            float xv[4], wv[6];
#pragma unroll
            for (int i = 0; i < 4; ++i) xv[i] = xt[(4 * ty + i) * 97 + kk];
#pragma unroll
            for (int j = 0; j < 6; ++j) wv[j] = wt[kk * 96 + tx + 16 * j];
#pragma unroll
            for (int i = 0; i < 4; ++i)
#pragma unroll
                for (int j = 0; j < 6; ++j)
                    acc[i][j] += xv[i] * wv[j];
        }
#pragma unroll
        for (int i = 0; i < 4; ++i) {
#pragma unroll
            for (int j = 0; j < 6; ++j) {
                int n = nch + tx + 16 * j;
                int t = t0 + 4 * ty + i;
                float v = acc[i][j] + bias[n];
                if (n < 96) outA[(size_t)t * 96 + n] = v;
                else        outB[(size_t)t * 96 + (n - 96)] = v;
            }
        }
    }
}

// ---------------------------------------------------------------------------
// K34: fused attention per (window, 32-row n-tile): S = scale*QK^T + relbias,
// softmax, O = P@V, out = O@wproj + bproj + shortcut(I_m). x2 may alias q
// (each block owns its token rows exclusively; reads q before writing x2).
// grid = 1024*5 = 5120 blocks, 256 threads. LDS 12800 floats = 51.2 KB.
// ---------------------------------------------------------------------------
__global__ __launch_bounds__(256) void k_attn(
    const float* qb, const float* __restrict__ kb, const float* __restrict__ vb,
    const float* __restrict__ relb, const float* __restrict__ wproj,
    const float* __restrict__ bproj, const float* __restrict__ Im,
    float* x2)
{
    __shared__ float smem[12800];
    int blk = blockIdx.x;
    int win = blk / 5, nt = blk % 5;
    int n0 = nt * 32;
    int tid = threadIdx.x;
    int ty = tid >> 5, tx = tid & 31;   // ty in [0,8): 4 n-rows each; tx: m/c lanes
    size_t wbase = (size_t)win * 150 * 96;

    // ---- Phase B: S accumulate (c split in two halves of 48) ----
    float* qt = smem;           // 32 x 49
    float* kt = smem + 1568;    // 160 x 49 (rows >=150 zeroed)
    float accS[4][5] = {};
    for (int ch = 0; ch < 2; ++ch) {
        int c0 = ch * 48;
        __syncthreads();
        for (int i = tid; i < 32 * 48; i += 256) {
            int nn = i / 48, cc = i % 48;
            int ng = n0 + nn;
            qt[nn * 49 + cc] = (ng < 150) ? qb[wbase + (size_t)ng * 96 + c0 + cc] : 0.f;
        }
        for (int i = tid; i < 160 * 48; i += 256) {
            int mm = i / 48, cc = i % 48;
            kt[mm * 49 + cc] = (mm < 150) ? kb[wbase + (size_t)mm * 96 + c0 + cc] : 0.f;
        }
        __syncthreads();
#pragma unroll 2
        for (int cc = 0; cc < 48; ++cc) {
            float qv[4], kv[5];
#pragma unroll
            for (int i = 0; i < 4; ++i) qv[i] = qt[(4 * ty + i) * 49 + cc];
#pragma unroll
            for (int g = 0; g < 5; ++g) kv[g] = kt[(tx + 32 * g) * 49 + cc];
#pragma unroll
            for (int i = 0; i < 4; ++i)
#pragma unroll
                for (int g = 0; g < 5; ++g)
                    accS[i][g] += qv[i] * kv[g];
        }
    }

    // ---- Softmax with relative-position bias (rows spread over 32 tx lanes) --
    float p[4][5];
#pragma unroll
    for (int i = 0; i < 4; ++i) {
        int nl = n0 + 4 * ty + i;
        if (nl > 149) nl = 149;            // padded rows: computed, never written
        int wd = nl / 30, rh = nl % 30;
        int wh = rh / 5, wwn = rh % 5;
        float s[5];
#pragma unroll
        for (int g = 0; g < 5; ++g) {
            int m = tx + 32 * g;
            if (m < 150) {
                int wd2 = m / 30, rh2 = m % 30;
                int wh2 = rh2 / 5, ww2 = rh2 % 5;
                int idx = (wd - wd2 + 4) * 99 + (wh - wh2 + 5) * 9 + (wwn - ww2 + 4);
                s[g] = accS[i][g] * SCALE + relb[idx];
            } else {
                s[g] = -1e30f;
            }
        }
        float mx = s[0];
#pragma unroll
        for (int g = 1; g < 5; ++g) mx = fmaxf(mx, s[g]);
        for (int off = 16; off; off >>= 1) mx = fmaxf(mx, __shfl_xor(mx, off, 32));
        float sum = 0.f;
#pragma unroll
        for (int g = 0; g < 5; ++g) { s[g] = __expf(s[g] - mx); sum += s[g]; }
        for (int off = 16; off; off >>= 1) sum += __shfl_xor(sum, off, 32);
        float inv = 1.f / sum;
#pragma unroll
        for (int g = 0; g < 5; ++g) p[i][g] = s[g] * inv;
    }

    // ---- Phase C: O = P @ V (m split in two halves of 80) ----
    __syncthreads();                        // all qt/kt reads done
    float* P = smem;                        // 32 x 160
    float* vt = smem + 5120;                // 80 x 96
#pragma unroll
    for (int i = 0; i < 4; ++i)
#pragma unroll
        for (int g = 0; g < 5; ++g)
            P[(4 * ty + i) * 160 + tx + 32 * g] = p[i][g];

    float accO[4][3] = {};
    for (int mh = 0; mh < 2; ++mh) {
        int m0 = mh * 80;
        __syncthreads();
        for (int i = tid; i < 80 * 96; i += 256) {
            int mm = i / 96, cc = i % 96;
            int mg = m0 + mm;
            vt[mm * 96 + cc] = (mg < 150) ? vb[wbase + (size_t)mg * 96 + cc] : 0.f;
        }
        __syncthreads();
#pragma unroll 2
        for (int mm = 0; mm < 80; ++mm) {
            float pv[4], vv[3];
#pragma unroll
            for (int i = 0; i < 4; ++i) pv[i] = P[(4 * ty + i) * 160 + m0 + mm];
#pragma unroll
            for (int g = 0; g < 3; ++g) vv[g] = vt[mm * 96 + tx + 32 * g];
#pragma unroll
            for (int i = 0; i < 4; ++i)
#pragma unroll
                for (int g = 0; g < 3; ++g)
                    accO[i][g] += pv[i] * vv[g];
        }
    }

    // ---- Phase D: out = O @ wproj + bproj + shortcut ----
    __syncthreads();
    float* at = smem;            // 32 x 97
    float* wp = smem + 3104;     // 96 x 96
#pragma unroll
    for (int i = 0; i < 4; ++i)
#pragma unroll
        for (int g = 0; g < 3; ++g)
            at[(4 * ty + i) * 97 + tx + 32 * g] = accO[i][g];
    for (int i = tid; i < 9216; i += 256) wp[i] = wproj[i];
    __syncthreads();

    int ty3 = tid >> 4, tx3 = tid & 15;   // 2 rows x 6 cols per thread
    float accP[2][6] = {};
#pragma unroll 4
    for (int kk = 0; kk < 96; ++kk) {
        float av[2], wv[6];
#pragma unroll
        for (int i = 0; i < 2; ++i) av[i] = at[(2 * ty3 + i) * 97 + kk];
#pragma unroll
        for (int j = 0; j < 6; ++j) wv[j] = wp[kk * 96 + tx3 + 16 * j];
#pragma unroll
        for (int i = 0; i < 2; ++i)
#pragma unroll
            for (int j = 0; j < 6; ++j)
                accP[i][j] += av[i] * wv[j];
    }

    int b = win >> 9, wr = win & 511;
    int d0 = wr >> 6, h0 = (wr >> 3) & 7, w0 = wr & 7;
#pragma unroll
    for (int i = 0; i < 2; ++i) {
        int nl = n0 + 2 * ty3 + i;
        if (nl >= 150) continue;
        int wd = nl / 30, rh = nl % 30, wh = rh / 5, wwn = rh % 5;
        int d = d0 * 5 + wd, h = h0 * 6 + wh, w = w0 * 5 + wwn;
        int sbase = d * 1920 + h * 40 + w;
        size_t tok = (size_t)win * 150 + nl;
#pragma unroll
        for (int j = 0; j < 6; ++j) {
            int c = tx3 + 16 * j;
            float sc = Im[(size_t)(b * 96 + c) * 76800 + sbase];
            x2[tok * 96 + c] = accP[i][j] + bproj[c] + sc;
        }
    }
}

// ---------------------------------------------------------------------------
// K5: fused MLP: x3 = x2 + gelu(ln2(x2) @ w1 + b1) @ w2 + b2 (in-place OK,
// per-element single owner). grid = 2400 (64 tokens), 256 threads.
// Hidden dim 384 processed in 12 chunks of 32.
// ---------------------------------------------------------------------------
__global__ __launch_bounds__(256) void k_mlp(
    const float* x2, const float* __restrict__ g2, const float* __restrict__ b2,
    const float* __restrict__ w1, const float* __restrict__ b1,
    const float* __restrict__ w2, const float* __restrict__ b2v,
    float* x3)
{
    __shared__ float ht[64 * 97];
    __shared__ float h1c[64 * 33];
    __shared__ float w1c[96 * 32];
    __shared__ float w2c[32 * 96];
    __shared__ float ms[64], rs[64];
    int tid = threadIdx.x;
    int t0 = blockIdx.x * 64;

    for (int i = tid; i < 64 * 96; i += 256) {
        int t = i / 96, c = i % 96;
        ht[t * 97 + c] = x2[(size_t)(t0 + t) * 96 + c];
    }
    __syncthreads();
    if (tid < 64) {
        float s = 0.f, s2 = 0.f;
        for (int c = 0; c < 96; ++c) {
            float v = ht[tid * 97 + c];
            s += v; s2 += v * v;
        }
        float m = s * (1.f / 96.f);
        float var = s2 * (1.f / 96.f) - m * m;
        ms[tid] = m;
        rs[tid] = rsqrtf(var + 1e-5f);
    }
    __syncthreads();
    for (int i = tid; i < 64 * 96; i += 256) {
        int t = i / 96, c = i % 96;
        ht[t * 97 + c] = (ht[t * 97 + c] - ms[t]) * rs[t] * g2[c] + b2[c];
    }

    int ty = tid >> 4, tx = tid & 15;
    float acc[4][6] = {};
    for (int chk = 0; chk < 384; chk += 32) {
        __syncthreads();
        for (int i = tid; i < 96 * 32; i += 256) {
            int kk = i / 32, jj = i % 32;
            w1c[i] = w1[kk * 384 + chk + jj];
        }
        for (int i = tid; i < 32 * 96; i += 256) {
            int jj = i / 96, cc = i % 96;
            w2c[i] = w2[(chk + jj) * 96 + cc];
        }
        __syncthreads();

        float ah[4][2] = {};
#pragma unroll 4
        for (int kk = 0; kk < 96; ++kk) {
            float hv[4];
#pragma unroll
            for (int i = 0; i < 4; ++i) hv[i] = ht[(4 * ty + i) * 97 + kk];
            float wv0 = w1c[kk * 32 + tx];
            float wv1 = w1c[kk * 32 + tx + 16];
#pragma unroll
            for (int i = 0; i < 4; ++i) {
                ah[i][0] += hv[i] * wv0;
                ah[i][1] += hv[i] * wv1;
            }
        }
#pragma unroll
        for (int i = 0; i < 4; ++i) {
#pragma unroll
            for (int j2 = 0; j2 < 2; ++j2) {
                int jj = tx + 16 * j2;
                float u = ah[i][j2] + b1[chk + jj];
                float tt = 0.79788456080286536f * (u + 0.044715f * u * u * u);
                float e = __expf(2.f * tt);
                float th = 1.f - 2.f / (e + 1.f);   // tanh(tt), overflow-safe
                h1c[(4 * ty + i) * 33 + jj] = 0.5f * u * (1.f + th);
            }
        }
        __syncthreads();
#pragma unroll 4
        for (int jj = 0; jj < 32; ++jj) {
            float hv2[4], wv[6];
#pragma unroll
            for (int i = 0; i < 4; ++i) hv2[i] = h1c[(4 * ty + i) * 33 + jj];
#pragma unroll
            for (int j = 0; j < 6; ++j) wv[j] = w2c[jj * 96 + tx + 16 * j];
#pragma unroll
            for (int i = 0; i < 4; ++i)
#pragma unroll
                for (int j = 0; j < 6; ++j)
                    acc[i][j] += hv2[i] * wv[j];
        }
    }
#pragma unroll
    for (int i = 0; i < 4; ++i) {
#pragma unroll
        for (int j = 0; j < 6; ++j) {
            int t = t0 + 4 * ty + i, c = tx + 16 * j;
            size_t o = (size_t)t * 96 + c;
            x3[o] = x2[o] + acc[i][j] + b2v[c];
        }
    }
}

// ---------------------------------------------------------------------------
// K6: 3x3x3 conv (96 -> 3 channels), zero pad. One thread per spatial point,
// all 3 output channels. x3 is in window-token order; weights staged in LDS.
// grid = 600, 256 threads (600*256 = 153600).
// ---------------------------------------------------------------------------
__global__ __launch_bounds__(256) void k_conv(
    const float* __restrict__ x3, const float* __restrict__ cw,
    const float* __restrict__ cb, float* __restrict__ out)
{
    __shared__ float wl[7776];   // [oc][ci][27], same flat layout as conv_w
    int tid = threadIdx.x;
    for (int i = tid; i < 7776; i += 256) wl[i] = cw[i];
    __syncthreads();

    int s = blockIdx.x * 256 + tid;
    int b = s / 76800, r = s % 76800;
    int d = r / 1920, h = (r / 40) % 48, w = r % 40;
    float a0 = 0.f, a1 = 0.f, a2 = 0.f;

    for (int dd = 0; dd < 3; ++dd) {
        int d2 = d + dd - 1;
        if ((unsigned)d2 >= 40u) continue;
        for (int hh = 0; hh < 3; ++hh) {
            int h2 = h + hh - 1;
            if ((unsigned)h2 >= 48u) continue;
            for (int ww = 0; ww < 3; ++ww) {
                int w2 = w + ww - 1;
                if ((unsigned)w2 >= 40u) continue;
                int kk = (dd * 3 + hh) * 3 + ww;
                const float4* xp =
                    (const float4*)(x3 + (size_t)tok_index(b, d2, h2, w2) * 96);
                const float* wb = wl + kk;
#pragma unroll 6
                for (int c4 = 0; c4 < 24; ++c4) {
                    float4 xv = xp[c4];
                    const float* w0p = wb + c4 * 108;           // 4 channels * 27
                    a0 += xv.x * w0p[0] + xv.y * w0p[27] + xv.z * w0p[54] + xv.w * w0p[81];
                    const float* w1p = w0p + 2592;
                    a1 += xv.x * w1p[0] + xv.y * w1p[27] + xv.z * w1p[54] + xv.w * w1p[81];
                    const float* w2p = w0p + 5184;
                    a2 += xv.x * w2p[0] + xv.y * w2p[27] + xv.z * w2p[54] + xv.w * w2p[81];
                }
            }
        }
    }
    out[(size_t)(b * 3 + 0) * 76800 + r] = a0 + cb[0];
    out[(size_t)(b * 3 + 1) * 76800 + r] = a1 + cb[1];
    out[(size_t)(b * 3 + 2) * 76800 + r] = a2 + cb[2];
}

// ---------------------------------------------------------------------------
extern "C" void kernel_launch(void* const* d_in, const int* in_sizes, int n_in,
                              void* d_out, int out_size, void* d_ws, size_t ws_size,
                              hipStream_t stream)
{
    (void)in_sizes; (void)n_in; (void)out_size;

    const float* Im  = (const float*)d_in[0];
    const float* If  = (const float*)d_in[1];
    const float* g1q = (const float*)d_in[2];
    const float* b1q = (const float*)d_in[3];
    const float* g1k = (const float*)d_in[4];
    const float* b1k = (const float*)d_in[5];
    const float* wq  = (const float*)d_in[6];
    const float* bq  = (const float*)d_in[7];
    const float* wkv = (const float*)d_in[8];
    const float* bkv = (const float*)d_in[9];
    const float* wpj = (const float*)d_in[10];
    const float* bpj = (const float*)d_in[11];
    const float* rb  = (const float*)d_in[12];
    const float* g2  = (const float*)d_in[13];
    const float* b2  = (const float*)d_in[14];
    const float* w1  = (const float*)d_in[15];
    const float* b1  = (const float*)d_in[16];
    const float* w2  = (const float*)d_in[17];
    const float* b2v = (const float*)d_in[18];
    const float* cw  = (const float*)d_in[19];
    const float* cb  = (const float*)d_in[20];
    float* out = (float*)d_out;

    size_t U = (size_t)NTOK * 96;               // 14,745,600 floats
    if (ws_size < 4 * U * sizeof(float)) return; // needs 236 MB scratch
    float* ws  = (float*)d_ws;
    float* xln = ws;           // u0, later reused as k
    float* yln = ws + U;       // u1
    float* qb  = ws + 2 * U;   // u2: q -> x2 -> x3 (in-place chain)
    float* vb  = ws + 3 * U;   // u3
    float* kbf = xln;          // k overwrites xln (dead after q projection)

    k_ln_transpose<<<3840, 256, 0, stream>>>(Im, If, g1q, b1q, g1k, b1k, xln, yln);
    k_gemm_proj<<<2400, 256, 0, stream>>>(xln, wq, bq, 96, qb, qb);
    k_gemm_proj<<<2400, 256, 0, stream>>>(yln, wkv, bkv, 192, kbf, vb);
    k_attn<<<5120, 256, 0, stream>>>(qb, kbf, vb, rb, wpj, bpj, Im, qb);
    k_mlp<<<2400, 256, 0, stream>>>(qb, g2, b2, w1, b1, w2, b2v, qb);
    k_conv<<<600, 256, 0, stream>>>(qb, cw, cb, out);
}

// Round 2
// 1290.022 us; speedup vs baseline: 1.5214x; 1.5214x over previous
//
#include <hip/hip_runtime.h>
#include <math.h>

// ---------------------------------------------------------------------------
// Swin-3D cross-attention block. Round 1: bf16 MFMA for MLP + projections.
// Token order everywhere = window-partitioned order:
//   win = ((b*8 + d/5)*8 + h/6)*8 + w/5 ; t = ((d%5)*6 + h%6)*5 + w%5
// Workspace (U = 153600*96 = 14,745,600 elements):
//   [0, U/2)      xlnb  (U bf16)
//   [U/2, U)      ylnb  (U bf16)
//   [U, 1.5U)     qb    (U bf16)
//   [1.5U, 2U)    kb    (U bf16)
//   [2U, 2.5U)    vb    (U bf16)
//   [2.5U, ...)   bf16 weights: wqT 9216 | wkvT 18432 | w1T 36864 | w2T 36864
//   [3U, 4U)      x2/x3 fp32 (attn out + residual, then MLP in-place)
// Total = 4U floats = 236 MB (same as round 0).
// ---------------------------------------------------------------------------

static constexpr int NTOK = 153600;
static constexpr float SCALE = 0.10206207261596575f; // 96^-0.5

typedef __bf16 bf16_t;
typedef __bf16 bf16x8 __attribute__((ext_vector_type(8)));
typedef float f32x4 __attribute__((ext_vector_type(4)));

__device__ __forceinline__ int tok_index(int b, int d, int h, int w) {
    int d0 = d / 5, wd = d % 5;
    int h0 = h / 6, wh = h % 6;
    int w0 = w / 5, ww = w % 5;
    int win = ((b * 8 + d0) * 8 + h0) * 8 + w0;
    return win * 150 + (wd * 6 + wh) * 5 + ww;
}

// gelu(tanh approx) = u * sigmoid(2*0.7978845608*(u + 0.044715 u^3))
__device__ __forceinline__ float gelu_f(float u) {
    float u2 = u * u;
    float arg = u * fmaf(0.0713549f, u2, 1.5957691f);
    float e = __expf(arg);
    float r = __builtin_amdgcn_rcpf(e + 1.f);
    return fmaf(-u, r, u);   // u*(1 - 1/(e+1)) = u*e/(e+1)
}

// ---------------------------------------------------------------------------
// K0: convert + transpose weights to bf16 [n][k] layouts.
// ---------------------------------------------------------------------------
__global__ __launch_bounds__(256) void k_prep_weights(
    const float* __restrict__ wq, const float* __restrict__ wkv,
    const float* __restrict__ w1, const float* __restrict__ w2,
    bf16_t* wqT, bf16_t* wkvT, bf16_t* w1T, bf16_t* w2T)
{
    int i = blockIdx.x * 256 + threadIdx.x;
    if (i < 9216)  wqT[i]  = (bf16_t)wq[(i % 96) * 96 + i / 96];    // [n*96+k]
    if (i < 18432) wkvT[i] = (bf16_t)wkv[(i % 96) * 192 + i / 96];  // n<192
    if (i < 36864) w1T[i]  = (bf16_t)w1[(i % 96) * 384 + i / 96];   // n<384
    if (i < 36864) w2T[i]  = (bf16_t)w2[(i % 384) * 96 + i / 384];  // [n*384+k]
}

// ---------------------------------------------------------------------------
// K1: transpose (B,C,D,H,W)->window-token order + LayerNorm, output bf16.
// grid = B*D*H = 3840 blocks, 256 threads.
// ---------------------------------------------------------------------------
__global__ __launch_bounds__(256) void k_ln_transpose(
    const float* __restrict__ Im, const float* __restrict__ If,
    const float* __restrict__ g1q, const float* __restrict__ b1q,
    const float* __restrict__ g1k, const float* __restrict__ b1k,
    bf16_t* __restrict__ xln, bf16_t* __restrict__ yln)
{
    __shared__ float tile[40 * 97];
    __shared__ float mean_s[40], rstd_s[40];
    int blk = blockIdx.x;
    int b = blk / (40 * 48);
    int rem = blk % (40 * 48);
    int d = rem / 48, h = rem % 48;
    int tid = threadIdx.x;

    for (int pass = 0; pass < 2; ++pass) {
        const float* src = pass ? If : Im;
        const float* gg = pass ? g1k : g1q;
        const float* bb = pass ? b1k : b1q;
        bf16_t* dst = pass ? yln : xln;

        for (int i = tid; i < 96 * 40; i += 256) {
            int c = i / 40, w = i % 40;
            tile[w * 97 + c] = src[(size_t)(b * 96 + c) * 76800 + d * 1920 + h * 40 + w];
        }
        __syncthreads();
        if (tid < 40) {
            float s = 0.f, s2 = 0.f;
            for (int c = 0; c < 96; ++c) {
                float v = tile[tid * 97 + c];
                s += v; s2 += v * v;
            }
            float m = s * (1.f / 96.f);
            float var = s2 * (1.f / 96.f) - m * m;
            mean_s[tid] = m;
            rstd_s[tid] = rsqrtf(var + 1e-5f);
        }
        __syncthreads();
        for (int i = tid; i < 40 * 96; i += 256) {
            int w = i / 96, c = i % 96;
            int tok = tok_index(b, d, h, w);
            float v = (tile[w * 97 + c] - mean_s[w]) * rstd_s[w] * gg[c] + bb[c];
            dst[(size_t)tok * 96 + c] = (bf16_t)v;
        }
        __syncthreads();
    }
}

// ---------------------------------------------------------------------------
// K2: MFMA projection: out[t][n] = X[t][:] @ W[:][n] + bias, bf16 in/out.
// WT is [N][96] bf16 (K-contiguous). N=96 -> outA only; N=192 -> k|v split.
// grid = 2400 (64 tokens/block), 256 threads = 4 waves; wave owns 16 rows.
// ---------------------------------------------------------------------------
__global__ __launch_bounds__(256) void k_proj_mfma(
    const bf16_t* __restrict__ X, const bf16_t* __restrict__ WT,
    const float* __restrict__ bias, int N,
    bf16_t* __restrict__ outA, bf16_t* __restrict__ outB)
{
    __shared__ bf16_t xs[64 * 104];   // rows padded to 104 (208 B, 16B mult)
    int tid = threadIdx.x;
    int t0 = blockIdx.x * 64;

    const uint4* xg = (const uint4*)(X + (size_t)t0 * 96);  // 12 x 16B per row
    uint4* xsv = (uint4*)xs;
    for (int i = tid; i < 768; i += 256) {
        int row = i / 12, c16 = i % 12;
        xsv[row * 13 + c16] = xg[i];
    }
    __syncthreads();

    int w = tid >> 6, l = tid & 63;
    int lm = l & 15, lk = (l >> 4) * 8;
    int m0 = w * 16;
    bf16x8 a[3];
#pragma unroll
    for (int kk = 0; kk < 3; ++kk)
        a[kk] = *(const bf16x8*)(xs + (m0 + lm) * 104 + kk * 32 + lk);

    int ntiles = N >> 4;
    for (int ti = 0; ti < ntiles; ++ti) {
        int n0 = ti * 16;
        f32x4 c = {0.f, 0.f, 0.f, 0.f};
        const bf16_t* wp = WT + (size_t)(n0 + lm) * 96 + lk;
        c = __builtin_amdgcn_mfma_f32_16x16x32_bf16(a[0], *(const bf16x8*)(wp), c, 0, 0, 0);
        c = __builtin_amdgcn_mfma_f32_16x16x32_bf16(a[1], *(const bf16x8*)(wp + 32), c, 0, 0, 0);
        c = __builtin_amdgcn_mfma_f32_16x16x32_bf16(a[2], *(const bf16x8*)(wp + 64), c, 0, 0, 0);
        int n = n0 + lm;
        float bs = bias[n];
        bf16_t* outp = (n < 96) ? outA : outB;
        int nn = (n < 96) ? n : n - 96;
#pragma unroll
        for (int r = 0; r < 4; ++r) {
            int t = t0 + m0 + (l >> 4) * 4 + r;
            outp[(size_t)t * 96 + nn] = (bf16_t)(c[r] + bs);
        }
    }
}

// ---------------------------------------------------------------------------
// K34: fused attention per (window, 32-row n-tile), fp32 compute, bf16 q/k/v.
// out = softmax(scale*QK^T + relbias) @ V @ wproj + bproj + shortcut(I_m).
// grid = 5120 blocks, 256 threads. LDS 12800 floats = 51.2 KB.
// ---------------------------------------------------------------------------
__global__ __launch_bounds__(256) void k_attn(
    const bf16_t* __restrict__ qb, const bf16_t* __restrict__ kb,
    const bf16_t* __restrict__ vb,
    const float* __restrict__ relb, const float* __restrict__ wproj,
    const float* __restrict__ bproj, const float* __restrict__ Im,
    float* __restrict__ x2)
{
    __shared__ float smem[12800];
    int blk = blockIdx.x;
    int win = blk / 5, nt = blk % 5;
    int n0 = nt * 32;
    int tid = threadIdx.x;
    int ty = tid >> 5, tx = tid & 31;
    size_t wbase = (size_t)win * 150 * 96;

    // ---- S = Q K^T (c split in two halves of 48) ----
    float* qt = smem;           // 32 x 49
    float* kt = smem + 1568;    // 160 x 49
    float accS[4][5] = {};
    for (int ch = 0; ch < 2; ++ch) {
        int c0 = ch * 48;
        __syncthreads();
        for (int i = tid; i < 32 * 48; i += 256) {
            int nn = i / 48, cc = i % 48;
            int ng = n0 + nn;
            qt[nn * 49 + cc] = (ng < 150) ? (float)qb[wbase + (size_t)ng * 96 + c0 + cc] : 0.f;
        }
        for (int i = tid; i < 160 * 48; i += 256) {
            int mm = i / 48, cc = i % 48;
            kt[mm * 49 + cc] = (mm < 150) ? (float)kb[wbase + (size_t)mm * 96 + c0 + cc] : 0.f;
        }
        __syncthreads();
#pragma unroll 2
        for (int cc = 0; cc < 48; ++cc) {
            float qv[4], kv[5];
#pragma unroll
            for (int i = 0; i < 4; ++i) qv[i] = qt[(4 * ty + i) * 49 + cc];
#pragma unroll
            for (int g = 0; g < 5; ++g) kv[g] = kt[(tx + 32 * g) * 49 + cc];
#pragma unroll
            for (int i = 0; i < 4; ++i)
#pragma unroll
                for (int g = 0; g < 5; ++g)
                    accS[i][g] += qv[i] * kv[g];
        }
    }

    // ---- softmax + relative position bias ----
    float p[4][5];
#pragma unroll
    for (int i = 0; i < 4; ++i) {
        int nl = n0 + 4 * ty + i;
        if (nl > 149) nl = 149;
        int wd = nl / 30, rh = nl % 30;
        int wh = rh / 5, wwn = rh % 5;
        float s[5];
#pragma unroll
        for (int g = 0; g < 5; ++g) {
            int m = tx + 32 * g;
            if (m < 150) {
                int wd2 = m / 30, rh2 = m % 30;
                int wh2 = rh2 / 5, ww2 = rh2 % 5;
                int idx = (wd - wd2 + 4) * 99 + (wh - wh2 + 5) * 9 + (wwn - ww2 + 4);
                s[g] = accS[i][g] * SCALE + relb[idx];
            } else {
                s[g] = -1e30f;
            }
        }
        float mx = s[0];
#pragma unroll
        for (int g = 1; g < 5; ++g) mx = fmaxf(mx, s[g]);
        for (int off = 16; off; off >>= 1) mx = fmaxf(mx, __shfl_xor(mx, off, 32));
        float sum = 0.f;
#pragma unroll
        for (int g = 0; g < 5; ++g) { s[g] = __expf(s[g] - mx); sum += s[g]; }
        for (int off = 16; off; off >>= 1) sum += __shfl_xor(sum, off, 32);
        float inv = 1.f / sum;
#pragma unroll
        for (int g = 0; g < 5; ++g) p[i][g] = s[g] * inv;
    }

    // ---- O = P @ V ----
    __syncthreads();
    float* P = smem;            // 32 x 160
    float* vt = smem + 5120;    // 80 x 96
#pragma unroll
    for (int i = 0; i < 4; ++i)
#pragma unroll
        for (int g = 0; g < 5; ++g)
            P[(4 * ty + i) * 160 + tx + 32 * g] = p[i][g];

    float accO[4][3] = {};
    for (int mh = 0; mh < 2; ++mh) {
        int m0 = mh * 80;
        __syncthreads();
        for (int i = tid; i < 80 * 96; i += 256) {
            int mm = i / 96, cc = i % 96;
            int mg = m0 + mm;
            vt[mm * 96 + cc] = (mg < 150) ? (float)vb[wbase + (size_t)mg * 96 + cc] : 0.f;
        }
        __syncthreads();
#pragma unroll 2
        for (int mm = 0; mm < 80; ++mm) {
            float pv[4], vv[3];
#pragma unroll
            for (int i = 0; i < 4; ++i) pv[i] = P[(4 * ty + i) * 160 + m0 + mm];
#pragma unroll
            for (int g = 0; g < 3; ++g) vv[g] = vt[mm * 96 + tx + 32 * g];
#pragma unroll
            for (int i = 0; i < 4; ++i)
#pragma unroll
                for (int g = 0; g < 3; ++g)
                    accO[i][g] += pv[i] * vv[g];
        }
    }

    // ---- out = O @ wproj + bproj + shortcut ----
    __syncthreads();
    float* at = smem;            // 32 x 97
    float* wp = smem + 3104;     // 96 x 96
#pragma unroll
    for (int i = 0; i < 4; ++i)
#pragma unroll
        for (int g = 0; g < 3; ++g)
            at[(4 * ty + i) * 97 + tx + 32 * g] = accO[i][g];
    for (int i = tid; i < 9216; i += 256) wp[i] = wproj[i];
    __syncthreads();

    int ty3 = tid >> 4, tx3 = tid & 15;
    float accP[2][6] = {};
#pragma unroll 4
    for (int kk = 0; kk < 96; ++kk) {
        float av[2], wv[6];
#pragma unroll
        for (int i = 0; i < 2; ++i) av[i] = at[(2 * ty3 + i) * 97 + kk];
#pragma unroll
        for (int j = 0; j < 6; ++j) wv[j] = wp[kk * 96 + tx3 + 16 * j];
#pragma unroll
        for (int i = 0; i < 2; ++i)
#pragma unroll
            for (int j = 0; j < 6; ++j)
                accP[i][j] += av[i] * wv[j];
    }

    int b = win >> 9, wr = win & 511;
    int d0 = wr >> 6, h0 = (wr >> 3) & 7, w0 = wr & 7;
#pragma unroll
    for (int i = 0; i < 2; ++i) {
        int nl = n0 + 2 * ty3 + i;
        if (nl >= 150) continue;
        int wd = nl / 30, rh = nl % 30, wh = rh / 5, wwn = rh % 5;
        int d = d0 * 5 + wd, h = h0 * 6 + wh, w = w0 * 5 + wwn;
        int sbase = d * 1920 + h * 40 + w;
        size_t tok = (size_t)win * 150 + nl;
#pragma unroll
        for (int j = 0; j < 6; ++j) {
            int c = tx3 + 16 * j;
            float sc = Im[(size_t)(b * 96 + c) * 76800 + sbase];
            x2[tok * 96 + c] = accP[i][j] + bproj[c] + sc;
        }
    }
}

// ---------------------------------------------------------------------------
// K5: MFMA MLP: x3 = x2 + gelu(ln2(x2) @ w1 + b1) @ w2 + b2 (in-place).
// grid = 2400 (64 tokens), 256 threads = 4 waves. Hidden in 3 chunks of 128;
// gelu'd chunk round-trips through wave-private LDS (C-layout -> A-layout).
// ---------------------------------------------------------------------------
__global__ __launch_bounds__(256) void k_mlp_mfma(
    const float* __restrict__ x2,
    const float* __restrict__ g2, const float* __restrict__ b2,
    const bf16_t* __restrict__ w1T, const float* __restrict__ b1,
    const bf16_t* __restrict__ w2T, const float* __restrict__ b2v,
    float* __restrict__ x3)
{
    __shared__ __align__(16) char smem[39424];
    float* xf = (float*)smem;                  // [64][100] fp32 (dies), then hs
    bf16_t* xs = (bf16_t*)(smem + 25600);      // [64][104] bf16 LN'd
    bf16_t* hs = (bf16_t*)smem;                // 4 waves x [16][136] bf16
    float* mrs = (float*)(smem + 38912);       // mean[64] | rstd[64]

    int tid = threadIdx.x;
    int t0 = blockIdx.x * 64;

    // load x2 tile (64 x 96 fp32 = 24 float4/row)
    const float4* xg = (const float4*)(x2 + (size_t)t0 * 96);
    for (int i = tid; i < 1536; i += 256) {
        int row = i / 24, c4 = i % 24;
        *(float4*)(xf + row * 100 + c4 * 4) = xg[i];
    }
    __syncthreads();

    // LN stats: 4 threads per token, 24 elements each, shuffle-combine
    {
        int t = tid >> 2, p = tid & 3;
        float s = 0.f, s2 = 0.f;
        const float* rp = xf + t * 100 + p * 24;
#pragma unroll 6
        for (int j = 0; j < 24; ++j) { float v = rp[j]; s += v; s2 += v * v; }
        s += __shfl_xor(s, 1); s += __shfl_xor(s, 2);
        s2 += __shfl_xor(s2, 1); s2 += __shfl_xor(s2, 2);
        if (p == 0) {
            float m = s * (1.f / 96.f);
            float var = s2 * (1.f / 96.f) - m * m;
            mrs[t] = m;
            mrs[64 + t] = rsqrtf(var + 1e-5f);
        }
    }
    __syncthreads();

    // normalize -> bf16 xs
    for (int i = tid; i < 6144; i += 256) {
        int t = i / 96, c = i % 96;
        float v = (xf[t * 100 + c] - mrs[t]) * mrs[64 + t] * g2[c] + b2[c];
        xs[t * 104 + c] = (bf16_t)v;
    }
    __syncthreads();   // xs ready; xf dead -> hs region usable

    int w = tid >> 6, l = tid & 63;
    int lm = l & 15, lk = (l >> 4) * 8;
    int m0 = w * 16;
    bf16_t* hw = hs + w * 16 * 136;   // wave-private 16 x 136

    bf16x8 a[3];
#pragma unroll
    for (int kk = 0; kk < 3; ++kk)
        a[kk] = *(const bf16x8*)(xs + (m0 + lm) * 104 + kk * 32 + lk);

    f32x4 acc2[6];
#pragma unroll
    for (int i = 0; i < 6; ++i) acc2[i] = (f32x4){0.f, 0.f, 0.f, 0.f};

    for (int cc = 0; cc < 3; ++cc) {
        // stage 1: h = gelu(xs @ w1_chunk + b1), 8 n-tiles of 16
#pragma unroll
        for (int ti = 0; ti < 8; ++ti) {
            int n = cc * 128 + ti * 16 + lm;
            const bf16_t* wp = w1T + (size_t)n * 96 + lk;
            f32x4 c1 = {0.f, 0.f, 0.f, 0.f};
            c1 = __builtin_amdgcn_mfma_f32_16x16x32_bf16(a[0], *(const bf16x8*)(wp), c1, 0, 0, 0);
            c1 = __builtin_amdgcn_mfma_f32_16x16x32_bf16(a[1], *(const bf16x8*)(wp + 32), c1, 0, 0, 0);
            c1 = __builtin_amdgcn_mfma_f32_16x16x32_bf16(a[2], *(const bf16x8*)(wp + 64), c1, 0, 0, 0);
            float bs = b1[n];
#pragma unroll
            for (int r = 0; r < 4; ++r) {
                int row = (l >> 4) * 4 + r;
                hw[row * 136 + ti * 16 + lm] = (bf16_t)gelu_f(c1[r] + bs);
            }
        }
        // stage 2: acc2 += h_chunk @ w2_chunk (wave-private, no barrier)
        bf16x8 ha[4];
#pragma unroll
        for (int kk = 0; kk < 4; ++kk)
            ha[kk] = *(const bf16x8*)(hw + lm * 136 + kk * 32 + lk);
#pragma unroll
        for (int ti = 0; ti < 6; ++ti) {
            const bf16_t* wp = w2T + (size_t)(ti * 16 + lm) * 384 + cc * 128 + lk;
#pragma unroll
            for (int kk = 0; kk < 4; ++kk)
                acc2[ti] = __builtin_amdgcn_mfma_f32_16x16x32_bf16(
                    ha[kk], *(const bf16x8*)(wp + kk * 32), acc2[ti], 0, 0, 0);
        }
    }

    // epilogue: residual + bias
#pragma unroll
    for (int ti = 0; ti < 6; ++ti) {
        int n = ti * 16 + lm;
        float bs = b2v[n];
#pragma unroll
        for (int r = 0; r < 4; ++r) {
            int t = t0 + m0 + (l >> 4) * 4 + r;
            size_t o = (size_t)t * 96 + n;
            x3[o] = x2[o] + acc2[ti][r] + bs;
        }
    }
}

// ---------------------------------------------------------------------------
// K6: 3x3x3 conv (96 -> 3 channels), zero pad, fp32. grid = 600, 256 thr.
// ---------------------------------------------------------------------------
__global__ __launch_bounds__(256) void k_conv(
    const float* __restrict__ x3, const float* __restrict__ cw,
    const float* __restrict__ cb, float* __restrict__ out)
{
    __shared__ float wl[7776];   // [oc][ci][27]
    int tid = threadIdx.x;
    for (int i = tid; i < 7776; i += 256) wl[i] = cw[i];
    __syncthreads();

    int s = blockIdx.x * 256 + tid;
    int b = s / 76800, r = s % 76800;
    int d = r / 1920, h = (r / 40) % 48, w = r % 40;
    float a0 = 0.f, a1 = 0.f, a2 = 0.f;

    for (int dd = 0; dd < 3; ++dd) {
        int d2 = d + dd - 1;
        if ((unsigned)d2 >= 40u) continue;
        for (int hh = 0; hh < 3; ++hh) {
            int h2 = h + hh - 1;
            if ((unsigned)h2 >= 48u) continue;
            for (int ww = 0; ww < 3; ++ww) {
                int w2 = w + ww - 1;
                if ((unsigned)w2 >= 40u) continue;
                int kk = (dd * 3 + hh) * 3 + ww;
                const float4* xp =
                    (const float4*)(x3 + (size_t)tok_index(b, d2, h2, w2) * 96);
                const float* wb = wl + kk;
#pragma unroll 6
                for (int c4 = 0; c4 < 24; ++c4) {
                    float4 xv = xp[c4];
                    const float* w0p = wb + c4 * 108;
                    a0 += xv.x * w0p[0] + xv.y * w0p[27] + xv.z * w0p[54] + xv.w * w0p[81];
                    const float* w1p = w0p + 2592;
                    a1 += xv.x * w1p[0] + xv.y * w1p[27] + xv.z * w1p[54] + xv.w * w1p[81];
                    const float* w2p = w0p + 5184;
                    a2 += xv.x * w2p[0] + xv.y * w2p[27] + xv.z * w2p[54] + xv.w * w2p[81];
                }
            }
        }
    }
    out[(size_t)(b * 3 + 0) * 76800 + r] = a0 + cb[0];
    out[(size_t)(b * 3 + 1) * 76800 + r] = a1 + cb[1];
    out[(size_t)(b * 3 + 2) * 76800 + r] = a2 + cb[2];
}

// ---------------------------------------------------------------------------
extern "C" void kernel_launch(void* const* d_in, const int* in_sizes, int n_in,
                              void* d_out, int out_size, void* d_ws, size_t ws_size,
                              hipStream_t stream)
{
    (void)in_sizes; (void)n_in; (void)out_size;

    const float* Im  = (const float*)d_in[0];
    const float* If  = (const float*)d_in[1];
    const float* g1q = (const float*)d_in[2];
    const float* b1q = (const float*)d_in[3];
    const float* g1k = (const float*)d_in[4];
    const float* b1k = (const float*)d_in[5];
    const float* wq  = (const float*)d_in[6];
    const float* bq  = (const float*)d_in[7];
    const float* wkv = (const float*)d_in[8];
    const float* bkv = (const float*)d_in[9];
    const float* wpj = (const float*)d_in[10];
    const float* bpj = (const float*)d_in[11];
    const float* rb  = (const float*)d_in[12];
    const float* g2  = (const float*)d_in[13];
    const float* b2  = (const float*)d_in[14];
    const float* w1  = (const float*)d_in[15];
    const float* b1  = (const float*)d_in[16];
    const float* w2  = (const float*)d_in[17];
    const float* b2v = (const float*)d_in[18];
    const float* cw  = (const float*)d_in[19];
    const float* cb  = (const float*)d_in[20];
    float* out = (float*)d_out;

    size_t U = (size_t)NTOK * 96;
    if (ws_size < 4 * U * sizeof(float)) return;
    float* ws = (float*)d_ws;
    bf16_t* xlnb = (bf16_t*)ws;                       // U bf16
    bf16_t* ylnb = (bf16_t*)(ws + U / 2);             // U bf16
    bf16_t* qb   = (bf16_t*)(ws + U);                 // U bf16
    bf16_t* kb   = (bf16_t*)(ws + 3 * U / 2);         // U bf16
    bf16_t* vb   = (bf16_t*)(ws + 2 * U);             // U bf16
    bf16_t* wqT  = (bf16_t*)(ws + 5 * U / 2);         // 9216
    bf16_t* wkvT = wqT + 9216;                        // 18432
    bf16_t* w1T  = wkvT + 18432;                      // 36864
    bf16_t* w2T  = w1T + 36864;                       // 36864
    float*  x2f  = ws + 3 * U;                        // U fp32 (x2 -> x3)

    k_prep_weights<<<144, 256, 0, stream>>>(wq, wkv, w1, w2, wqT, wkvT, w1T, w2T);
    k_ln_transpose<<<3840, 256, 0, stream>>>(Im, If, g1q, b1q, g1k, b1k, xlnb, ylnb);
    k_proj_mfma<<<2400, 256, 0, stream>>>(xlnb, wqT, bq, 96, qb, qb);
    k_proj_mfma<<<2400, 256, 0, stream>>>(ylnb, wkvT, bkv, 192, kb, vb);
    k_attn<<<5120, 256, 0, stream>>>(qb, kb, vb, rb, wpj, bpj, Im, x2f);
    k_mlp_mfma<<<2400, 256, 0, stream>>>(x2f, g2, b2, w1T, b1, w2T, b2v, x2f);
    k_conv<<<600, 256, 0, stream>>>(x2f, cw, cb, out);
}

// Round 3
// 993.086 us; speedup vs baseline: 1.9763x; 1.2990x over previous
//
#include <hip/hip_runtime.h>
#include <math.h>

// ---------------------------------------------------------------------------
// Swin-3D cross-attention block. Round 2: full-MFMA attention.
// Token order = window-partitioned:
//   win = ((b*8 + d/5)*8 + h/6)*8 + w/5 ; t = ((d%5)*6 + h%6)*5 + w%5
// Workspace layout (fp32 offsets, U = 153600*96 = 14,745,600):
//   [0,U/2)   xlnb bf16      [U/2,U)  ylnb bf16
//   [U,1.5U)  qb bf16        [1.5U,2U) kb bf16
//   [2U,+7.86M) vT bf16 [win][96][160]
//   then bf16 weights wqT|wkvT|w1T|w2T|wpjT and fp32 bias_mat[160][160]
//   [3U,4U)   x2 fp32 (K1 writes Im shortcut; attn/MLP accumulate in place)
// ---------------------------------------------------------------------------

static constexpr int NTOK = 153600;
static constexpr float SCALE = 0.10206207261596575f; // 96^-0.5

typedef __bf16 bf16_t;
typedef __bf16 bf16x8 __attribute__((ext_vector_type(8)));
typedef float f32x4 __attribute__((ext_vector_type(4)));

__device__ __forceinline__ int tok_index(int b, int d, int h, int w) {
    int d0 = d / 5, wd = d % 5;
    int h0 = h / 6, wh = h % 6;
    int w0 = w / 5, ww = w % 5;
    int win = ((b * 8 + d0) * 8 + h0) * 8 + w0;
    return win * 150 + (wd * 6 + wh) * 5 + ww;
}

__device__ __forceinline__ float gelu_f(float u) {
    float u2 = u * u;
    float arg = u * fmaf(0.0713549f, u2, 1.5957691f);
    float e = __expf(arg);
    float r = __builtin_amdgcn_rcpf(e + 1.f);
    return fmaf(-u, r, u);
}

// ---------------------------------------------------------------------------
// K0: weight convert/transpose to bf16 [n][k] + fp32 bias matrix [160][160].
// ---------------------------------------------------------------------------
__global__ __launch_bounds__(256) void k_prep_weights(
    const float* __restrict__ wq, const float* __restrict__ wkv,
    const float* __restrict__ w1, const float* __restrict__ w2,
    const float* __restrict__ wproj, const float* __restrict__ relb,
    bf16_t* wqT, bf16_t* wkvT, bf16_t* w1T, bf16_t* w2T, bf16_t* wpjT,
    float* bias_mat)
{
    int i = blockIdx.x * 256 + threadIdx.x;
    if (i < 9216)  wqT[i]  = (bf16_t)wq[(i % 96) * 96 + i / 96];
    if (i < 18432) wkvT[i] = (bf16_t)wkv[(i % 96) * 192 + i / 96];
    if (i < 36864) w1T[i]  = (bf16_t)w1[(i % 96) * 384 + i / 96];
    if (i < 36864) w2T[i]  = (bf16_t)w2[(i % 384) * 96 + i / 384];
    if (i < 9216)  wpjT[i] = (bf16_t)wproj[(i % 96) * 96 + i / 96];
    if (i < 25600) {
        int row = i / 160, col = i % 160;
        float v;
        if (col >= 150) v = -1e30f;
        else if (row >= 150) v = 0.f;
        else {
            int wd1 = row / 30, rh1 = row % 30, wh1 = rh1 / 5, ww1 = rh1 % 5;
            int wd2 = col / 30, rh2 = col % 30, wh2 = rh2 / 5, ww2 = rh2 % 5;
            int idx = (wd1 - wd2 + 4) * 99 + (wh1 - wh2 + 5) * 9 + (ww1 - ww2 + 4);
            v = relb[idx];
        }
        bias_mat[i] = v;
    }
}

// ---------------------------------------------------------------------------
// K1: transpose->token order + LayerNorm (bf16 out) + fp32 Im shortcut to x2.
// grid = 3840, 256 threads.
// ---------------------------------------------------------------------------
__global__ __launch_bounds__(256) void k_ln_transpose(
    const float* __restrict__ Im, const float* __restrict__ If,
    const float* __restrict__ g1q, const float* __restrict__ b1q,
    const float* __restrict__ g1k, const float* __restrict__ b1k,
    bf16_t* __restrict__ xln, bf16_t* __restrict__ yln,
    float* __restrict__ x2s)
{
    __shared__ float tile[40 * 97];
    __shared__ float mean_s[40], rstd_s[40];
    int blk = blockIdx.x;
    int b = blk / (40 * 48);
    int rem = blk % (40 * 48);
    int d = rem / 48, h = rem % 48;
    int tid = threadIdx.x;

    for (int pass = 0; pass < 2; ++pass) {
        const float* src = pass ? If : Im;
        const float* gg = pass ? g1k : g1q;
        const float* bb = pass ? b1k : b1q;
        bf16_t* dst = pass ? yln : xln;

        for (int i = tid; i < 96 * 40; i += 256) {
            int c = i / 40, w = i % 40;
            tile[w * 97 + c] = src[(size_t)(b * 96 + c) * 76800 + d * 1920 + h * 40 + w];
        }
        __syncthreads();
        if (tid < 40) {
            float s = 0.f, s2 = 0.f;
            for (int c = 0; c < 96; ++c) {
                float v = tile[tid * 97 + c];
                s += v; s2 += v * v;
            }
            float m = s * (1.f / 96.f);
            float var = s2 * (1.f / 96.f) - m * m;
            mean_s[tid] = m;
            rstd_s[tid] = rsqrtf(var + 1e-5f);
        }
        __syncthreads();
        for (int i = tid; i < 40 * 96; i += 256) {
            int w = i / 96, c = i % 96;
            int tok = tok_index(b, d, h, w);
            float raw = tile[w * 97 + c];
            float v = (raw - mean_s[w]) * rstd_s[w] * gg[c] + bb[c];
            dst[(size_t)tok * 96 + c] = (bf16_t)v;
            if (pass == 0) x2s[(size_t)tok * 96 + c] = raw;   // shortcut
        }
        __syncthreads();
    }
}

// ---------------------------------------------------------------------------
// K2: MFMA projection. WT is [N][96] bf16. N=96 -> qb only.
// N=192 -> n<96 writes kb [t][c]; n>=96 writes vT [win][c][160].
// grid = 2400 (64 tokens/block), 256 threads = 4 waves.
// ---------------------------------------------------------------------------
__global__ __launch_bounds__(256) void k_proj_mfma(
    const bf16_t* __restrict__ X, const bf16_t* __restrict__ WT,
    const float* __restrict__ bias, int N,
    bf16_t* __restrict__ outA, bf16_t* __restrict__ vT)
{
    __shared__ bf16_t xs[64 * 104];
    int tid = threadIdx.x;
    int t0 = blockIdx.x * 64;

    const uint4* xg = (const uint4*)(X + (size_t)t0 * 96);
    uint4* xsv = (uint4*)xs;
    for (int i = tid; i < 768; i += 256) {
        int row = i / 12, c16 = i % 12;
        xsv[row * 13 + c16] = xg[i];
    }
    __syncthreads();

    int w = tid >> 6, l = tid & 63;
    int lm = l & 15, lk = (l >> 4) * 8;
    int m0 = w * 16;
    bf16x8 a[3];
#pragma unroll
    for (int kk = 0; kk < 3; ++kk)
        a[kk] = *(const bf16x8*)(xs + (m0 + lm) * 104 + kk * 32 + lk);

    int trow[4], twin[4], tm[4];
#pragma unroll
    for (int r = 0; r < 4; ++r) {
        int t = t0 + m0 + (l >> 4) * 4 + r;
        trow[r] = t; twin[r] = t / 150; tm[r] = t - twin[r] * 150;
    }

    int ntiles = N >> 4;
    for (int ti = 0; ti < ntiles; ++ti) {
        int n0 = ti * 16;
        f32x4 c = {0.f, 0.f, 0.f, 0.f};
        const bf16_t* wp = WT + (size_t)(n0 + lm) * 96 + lk;
        c = __builtin_amdgcn_mfma_f32_16x16x32_bf16(a[0], *(const bf16x8*)(wp), c, 0, 0, 0);
        c = __builtin_amdgcn_mfma_f32_16x16x32_bf16(a[1], *(const bf16x8*)(wp + 32), c, 0, 0, 0);
        c = __builtin_amdgcn_mfma_f32_16x16x32_bf16(a[2], *(const bf16x8*)(wp + 64), c, 0, 0, 0);
        int n = n0 + lm;
        float bs = bias[n];
        if (n < 96) {
#pragma unroll
            for (int r = 0; r < 4; ++r)
                outA[(size_t)trow[r] * 96 + n] = (bf16_t)(c[r] + bs);
        } else {
            int cc = n - 96;
#pragma unroll
            for (int r = 0; r < 4; ++r)
                vT[((size_t)twin[r] * 96 + cc) * 160 + tm[r]] = (bf16_t)(c[r] + bs);
        }
    }
}

// ---------------------------------------------------------------------------
// K34: MFMA attention. One wave per (window, 32-row slab): grid 5120 x 64.
// S = Q@K^T (B-frags straight from global kb), softmax with precomputed
// bias_mat (mask folded in), P->LDS->A-frags, O = P@vT, O->LDS->A-frags,
// x2 += O@wprojT + bproj (x2 pre-filled with shortcut by K1).
// ---------------------------------------------------------------------------
__global__ __launch_bounds__(64) void k_attn_mfma(
    const bf16_t* __restrict__ qb, const bf16_t* __restrict__ kb,
    const bf16_t* __restrict__ vT, const bf16_t* __restrict__ wpjT,
    const float* __restrict__ bias_mat, const float* __restrict__ bproj,
    float* __restrict__ x2)
{
    __shared__ __align__(16) bf16_t pls[16 * 168];
    int blk = blockIdx.x;
    int win = blk / 5, slab = blk % 5;
    int l = threadIdx.x;
    int lm = l & 15, lq = l >> 4, lk8 = lq * 8;
    size_t wbase = (size_t)win * 150 * 96;
    size_t vbase = (size_t)win * 96 * 160;

    for (int rt = 0; rt < 2; ++rt) {
        int r0 = slab * 32 + rt * 16;

        // ---- S = Q K^T ----
        bf16x8 aq[3];
#pragma unroll
        for (int kk = 0; kk < 3; ++kk)
            aq[kk] = *(const bf16x8*)(qb + wbase + (size_t)(r0 + lm) * 96 + kk * 32 + lk8);

        f32x4 s[10];
#pragma unroll
        for (int nt = 0; nt < 10; ++nt) {
            f32x4 acc = {0.f, 0.f, 0.f, 0.f};
            const bf16_t* kp = kb + wbase + (size_t)(nt * 16 + lm) * 96 + lk8;
            acc = __builtin_amdgcn_mfma_f32_16x16x32_bf16(aq[0], *(const bf16x8*)(kp), acc, 0, 0, 0);
            acc = __builtin_amdgcn_mfma_f32_16x16x32_bf16(aq[1], *(const bf16x8*)(kp + 32), acc, 0, 0, 0);
            acc = __builtin_amdgcn_mfma_f32_16x16x32_bf16(aq[2], *(const bf16x8*)(kp + 64), acc, 0, 0, 0);
            s[nt] = acc;
        }

        // ---- softmax (bias+mask folded into bias_mat) ----
#pragma unroll
        for (int r = 0; r < 4; ++r) {
            int grow = r0 + lq * 4 + r;
            float rowmax = -3.0e38f;
#pragma unroll
            for (int nt = 0; nt < 10; ++nt) {
                float bv = bias_mat[grow * 160 + nt * 16 + lm];
                float v = fmaf(s[nt][r], SCALE, bv);
                s[nt][r] = v;
                rowmax = fmaxf(rowmax, v);
            }
            rowmax = fmaxf(rowmax, __shfl_xor(rowmax, 1));
            rowmax = fmaxf(rowmax, __shfl_xor(rowmax, 2));
            rowmax = fmaxf(rowmax, __shfl_xor(rowmax, 4));
            rowmax = fmaxf(rowmax, __shfl_xor(rowmax, 8));
            float ssum = 0.f;
#pragma unroll
            for (int nt = 0; nt < 10; ++nt) {
                float e = __expf(s[nt][r] - rowmax);
                s[nt][r] = e;
                ssum += e;
            }
            ssum += __shfl_xor(ssum, 1);
            ssum += __shfl_xor(ssum, 2);
            ssum += __shfl_xor(ssum, 4);
            ssum += __shfl_xor(ssum, 8);
            float inv = 1.f / ssum;
            int lrow = lq * 4 + r;
#pragma unroll
            for (int nt = 0; nt < 10; ++nt)
                pls[lrow * 168 + nt * 16 + lm] = (bf16_t)(s[nt][r] * inv);
        }
        __syncthreads();

        // ---- O = P @ V (vT B-frags straight from global) ----
        f32x4 o[6];
#pragma unroll
        for (int ct = 0; ct < 6; ++ct) o[ct] = (f32x4){0.f, 0.f, 0.f, 0.f};
#pragma unroll
        for (int kf = 0; kf < 5; ++kf) {
            bf16x8 ap = *(const bf16x8*)(pls + lm * 168 + kf * 32 + lk8);
#pragma unroll
            for (int ct = 0; ct < 6; ++ct) {
                const bf16_t* vp = vT + vbase + (size_t)(ct * 16 + lm) * 160 + kf * 32 + lk8;
                o[ct] = __builtin_amdgcn_mfma_f32_16x16x32_bf16(ap, *(const bf16x8*)(vp), o[ct], 0, 0, 0);
            }
        }
        __syncthreads();

        // ---- O -> LDS (A-layout staging), reuse pls as [16][104] ----
#pragma unroll
        for (int ct = 0; ct < 6; ++ct)
#pragma unroll
            for (int r = 0; r < 4; ++r)
                pls[(lq * 4 + r) * 104 + ct * 16 + lm] = (bf16_t)o[ct][r];
        __syncthreads();

        // ---- x2 += O @ wprojT + bproj ----
        bf16x8 ao[3];
#pragma unroll
        for (int kk = 0; kk < 3; ++kk)
            ao[kk] = *(const bf16x8*)(pls + lm * 104 + kk * 32 + lk8);
        f32x4 pj[6];
#pragma unroll
        for (int ct = 0; ct < 6; ++ct) {
            f32x4 acc = {0.f, 0.f, 0.f, 0.f};
            const bf16_t* wp = wpjT + (size_t)(ct * 16 + lm) * 96 + lk8;
            acc = __builtin_amdgcn_mfma_f32_16x16x32_bf16(ao[0], *(const bf16x8*)(wp), acc, 0, 0, 0);
            acc = __builtin_amdgcn_mfma_f32_16x16x32_bf16(ao[1], *(const bf16x8*)(wp + 32), acc, 0, 0, 0);
            acc = __builtin_amdgcn_mfma_f32_16x16x32_bf16(ao[2], *(const bf16x8*)(wp + 64), acc, 0, 0, 0);
            pj[ct] = acc;
        }
#pragma unroll
        for (int r = 0; r < 4; ++r) {
            int gr = r0 + lq * 4 + r;
            if (gr < 150) {
                size_t t = (size_t)win * 150 + gr;
#pragma unroll
                for (int ct = 0; ct < 6; ++ct) {
                    int c = ct * 16 + lm;
                    size_t off = t * 96 + c;
                    x2[off] = x2[off] + pj[ct][r] + bproj[c];
                }
            }
        }
        __syncthreads();
    }
}

// ---------------------------------------------------------------------------
// K5: MFMA MLP: x3 = x2 + gelu(ln2(x2) @ w1 + b1) @ w2 + b2 (in-place).
// grid = 2400 (64 tokens), 256 threads = 4 waves.
// ---------------------------------------------------------------------------
__global__ __launch_bounds__(256) void k_mlp_mfma(
    const float* __restrict__ x2,
    const float* __restrict__ g2, const float* __restrict__ b2,
    const bf16_t* __restrict__ w1T, const float* __restrict__ b1,
    const bf16_t* __restrict__ w2T, const float* __restrict__ b2v,
    float* __restrict__ x3)
{
    __shared__ __align__(16) char smem[39424];
    float* xf = (float*)smem;                  // [64][100] fp32 (dies)
    bf16_t* xs = (bf16_t*)(smem + 25600);      // [64][104] bf16 LN'd
    bf16_t* hs = (bf16_t*)smem;                // 4 waves x [16][136] bf16
    float* mrs = (float*)(smem + 38912);

    int tid = threadIdx.x;
    int t0 = blockIdx.x * 64;

    const float4* xg = (const float4*)(x2 + (size_t)t0 * 96);
    for (int i = tid; i < 1536; i += 256) {
        int row = i / 24, c4 = i % 24;
        *(float4*)(xf + row * 100 + c4 * 4) = xg[i];
    }
    __syncthreads();

    {
        int t = tid >> 2, p = tid & 3;
        float s = 0.f, s2 = 0.f;
        const float* rp = xf + t * 100 + p * 24;
#pragma unroll 6
        for (int j = 0; j < 24; ++j) { float v = rp[j]; s += v; s2 += v * v; }
        s += __shfl_xor(s, 1); s += __shfl_xor(s, 2);
        s2 += __shfl_xor(s2, 1); s2 += __shfl_xor(s2, 2);
        if (p == 0) {
            float m = s * (1.f / 96.f);
            float var = s2 * (1.f / 96.f) - m * m;
            mrs[t] = m;
            mrs[64 + t] = rsqrtf(var + 1e-5f);
        }
    }
    __syncthreads();

    for (int i = tid; i < 6144; i += 256) {
        int t = i / 96, c = i % 96;
        float v = (xf[t * 100 + c] - mrs[t]) * mrs[64 + t] * g2[c] + b2[c];
        xs[t * 104 + c] = (bf16_t)v;
    }
    __syncthreads();

    int w = tid >> 6, l = tid & 63;
    int lm = l & 15, lk = (l >> 4) * 8;
    int m0 = w * 16;
    bf16_t* hw = hs + w * 16 * 136;

    bf16x8 a[3];
#pragma unroll
    for (int kk = 0; kk < 3; ++kk)
        a[kk] = *(const bf16x8*)(xs + (m0 + lm) * 104 + kk * 32 + lk);

    f32x4 acc2[6];
#pragma unroll
    for (int i = 0; i < 6; ++i) acc2[i] = (f32x4){0.f, 0.f, 0.f, 0.f};

    for (int cc = 0; cc < 3; ++cc) {
#pragma unroll
        for (int ti = 0; ti < 8; ++ti) {
            int n = cc * 128 + ti * 16 + lm;
            const bf16_t* wp = w1T + (size_t)n * 96 + lk;
            f32x4 c1 = {0.f, 0.f, 0.f, 0.f};
            c1 = __builtin_amdgcn_mfma_f32_16x16x32_bf16(a[0], *(const bf16x8*)(wp), c1, 0, 0, 0);
            c1 = __builtin_amdgcn_mfma_f32_16x16x32_bf16(a[1], *(const bf16x8*)(wp + 32), c1, 0, 0, 0);
            c1 = __builtin_amdgcn_mfma_f32_16x16x32_bf16(a[2], *(const bf16x8*)(wp + 64), c1, 0, 0, 0);
            float bs = b1[n];
#pragma unroll
            for (int r = 0; r < 4; ++r) {
                int row = (l >> 4) * 4 + r;
                hw[row * 136 + ti * 16 + lm] = (bf16_t)gelu_f(c1[r] + bs);
            }
        }
        bf16x8 ha[4];
#pragma unroll
        for (int kk = 0; kk < 4; ++kk)
            ha[kk] = *(const bf16x8*)(hw + lm * 136 + kk * 32 + lk);
#pragma unroll
        for (int ti = 0; ti < 6; ++ti) {
            const bf16_t* wp = w2T + (size_t)(ti * 16 + lm) * 384 + cc * 128 + lk;
#pragma unroll
            for (int kk = 0; kk < 4; ++kk)
                acc2[ti] = __builtin_amdgcn_mfma_f32_16x16x32_bf16(
                    ha[kk], *(const bf16x8*)(wp + kk * 32), acc2[ti], 0, 0, 0);
        }
    }

#pragma unroll
    for (int ti = 0; ti < 6; ++ti) {
        int n = ti * 16 + lm;
        float bs = b2v[n];
#pragma unroll
        for (int r = 0; r < 4; ++r) {
            int t = t0 + m0 + (l >> 4) * 4 + r;
            size_t o = (size_t)t * 96 + n;
            x3[o] = x2[o] + acc2[ti][r] + bs;
        }
    }
}

// ---------------------------------------------------------------------------
// K6: 3x3x3 conv (96 -> 3), zero pad, fp32. grid = 600, 256 threads.
// ---------------------------------------------------------------------------
__global__ __launch_bounds__(256) void k_conv(
    const float* __restrict__ x3, const float* __restrict__ cw,
    const float* __restrict__ cb, float* __restrict__ out)
{
    __shared__ float wl[7776];
    int tid = threadIdx.x;
    for (int i = tid; i < 7776; i += 256) wl[i] = cw[i];
    __syncthreads();

    int s = blockIdx.x * 256 + tid;
    int b = s / 76800, r = s % 76800;
    int d = r / 1920, h = (r / 40) % 48, w = r % 40;
    float a0 = 0.f, a1 = 0.f, a2 = 0.f;

    for (int dd = 0; dd < 3; ++dd) {
        int d2 = d + dd - 1;
        if ((unsigned)d2 >= 40u) continue;
        for (int hh = 0; hh < 3; ++hh) {
            int h2 = h + hh - 1;
            if ((unsigned)h2 >= 48u) continue;
            for (int ww = 0; ww < 3; ++ww) {
                int w2 = w + ww - 1;
                if ((unsigned)w2 >= 40u) continue;
                int kk = (dd * 3 + hh) * 3 + ww;
                const float4* xp =
                    (const float4*)(x3 + (size_t)tok_index(b, d2, h2, w2) * 96);
                const float* wb = wl + kk;
#pragma unroll 6
                for (int c4 = 0; c4 < 24; ++c4) {
                    float4 xv = xp[c4];
                    const float* w0p = wb + c4 * 108;
                    a0 += xv.x * w0p[0] + xv.y * w0p[27] + xv.z * w0p[54] + xv.w * w0p[81];
                    const float* w1p = w0p + 2592;
                    a1 += xv.x * w1p[0] + xv.y * w1p[27] + xv.z * w1p[54] + xv.w * w1p[81];
                    const float* w2p = w0p + 5184;
                    a2 += xv.x * w2p[0] + xv.y * w2p[27] + xv.z * w2p[54] + xv.w * w2p[81];
                }
            }
        }
    }
    out[(size_t)(b * 3 + 0) * 76800 + r] = a0 + cb[0];
    out[(size_t)(b * 3 + 1) * 76800 + r] = a1 + cb[1];
    out[(size_t)(b * 3 + 2) * 76800 + r] = a2 + cb[2];
}

// ---------------------------------------------------------------------------
extern "C" void kernel_launch(void* const* d_in, const int* in_sizes, int n_in,
                              void* d_out, int out_size, void* d_ws, size_t ws_size,
                              hipStream_t stream)
{
    (void)in_sizes; (void)n_in; (void)out_size;

    const float* Im  = (const float*)d_in[0];
    const float* If  = (const float*)d_in[1];
    const float* g1q = (const float*)d_in[2];
    const float* b1q = (const float*)d_in[3];
    const float* g1k = (const float*)d_in[4];
    const float* b1k = (const float*)d_in[5];
    const float* wq  = (const float*)d_in[6];
    const float* bq  = (const float*)d_in[7];
    const float* wkv = (const float*)d_in[8];
    const float* bkv = (const float*)d_in[9];
    const float* wpj = (const float*)d_in[10];
    const float* bpj = (const float*)d_in[11];
    const float* rb  = (const float*)d_in[12];
    const float* g2  = (const float*)d_in[13];
    const float* b2  = (const float*)d_in[14];
    const float* w1  = (const float*)d_in[15];
    const float* b1  = (const float*)d_in[16];
    const float* w2  = (const float*)d_in[17];
    const float* b2v = (const float*)d_in[18];
    const float* cw  = (const float*)d_in[19];
    const float* cb  = (const float*)d_in[20];
    float* out = (float*)d_out;

    size_t U = (size_t)NTOK * 96;
    if (ws_size < 4 * U * sizeof(float)) return;
    float* ws = (float*)d_ws;
    bf16_t* xlnb = (bf16_t*)ws;                        // U bf16
    bf16_t* ylnb = (bf16_t*)(ws + U / 2);              // U bf16
    bf16_t* qb   = (bf16_t*)(ws + U);                  // U bf16
    bf16_t* kb   = (bf16_t*)(ws + 3 * U / 2);          // U bf16
    bf16_t* vT   = (bf16_t*)(ws + 2 * U);              // 1024*96*160 bf16
    float*  wtail = ws + 2 * U + (1024 * 96 * 160) / 2;
    bf16_t* wqT  = (bf16_t*)wtail;                     // 9216
    bf16_t* wkvT = wqT + 9216;                         // 18432
    bf16_t* w1T  = wkvT + 18432;                       // 36864
    bf16_t* w2T  = w1T + 36864;                        // 36864
    bf16_t* wpjT = w2T + 36864;                        // 9216
    float*  bias_mat = (float*)(wpjT + 9216 + 2);      // 25600 fp32 (aligned)
    float*  x2f  = ws + 3 * U;                         // U fp32

    k_prep_weights<<<144, 256, 0, stream>>>(wq, wkv, w1, w2, wpj, rb,
                                            wqT, wkvT, w1T, w2T, wpjT, bias_mat);
    k_ln_transpose<<<3840, 256, 0, stream>>>(Im, If, g1q, b1q, g1k, b1k,
                                             xlnb, ylnb, x2f);
    k_proj_mfma<<<2400, 256, 0, stream>>>(xlnb, wqT, bq, 96, qb, nullptr);
    k_proj_mfma<<<2400, 256, 0, stream>>>(ylnb, wkvT, bkv, 192, kb, vT);
    k_attn_mfma<<<5120, 64, 0, stream>>>(qb, kb, vT, wpjT, bias_mat, bpj, x2f);
    k_mlp_mfma<<<2400, 256, 0, stream>>>(x2f, g2, b2, w1T, b1, w2T, b2v, x2f);
    k_conv<<<600, 256, 0, stream>>>(x2f, cw, cb, out);
}

// Round 4
// 825.684 us; speedup vs baseline: 2.3770x; 1.2027x over previous
//
#include <hip/hip_runtime.h>
#include <math.h>

// ---------------------------------------------------------------------------
// Swin-3D cross-attention block. Round 3: spatial-order bf16 conv input +
// float4-broadcast conv weights (fixes k_conv's 683MB over-fetch + LDS issue).
// Token order = window-partitioned:
//   win = ((b*8 + d/5)*8 + h/6)*8 + w/5 ; t = ((d%5)*6 + h%6)*5 + w%5
// Workspace layout (fp32 offsets, U = 153600*96 = 14,745,600):
//   [0,U/2)   xlnb bf16   --later reused as-> xc bf16 (spatial-order conv in)
//   [U/2,U)   ylnb bf16
//   [U,1.5U)  qb bf16     [1.5U,2U) kb bf16
//   [2U,+7.86M) vT bf16 [win][96][160]
//   then bf16 weights wqT|wkvT|w1T|w2T|wpjT, fp32 bias_mat[160][160], cwT
//   [3U,4U)   x2 fp32 (K1 writes Im shortcut; attn accumulates in place)
// ---------------------------------------------------------------------------

static constexpr int NTOK = 153600;
static constexpr float SCALE = 0.10206207261596575f; // 96^-0.5

typedef __bf16 bf16_t;
typedef __bf16 bf16x8 __attribute__((ext_vector_type(8)));
typedef float f32x4 __attribute__((ext_vector_type(4)));

__device__ __forceinline__ int tok_index(int b, int d, int h, int w) {
    int d0 = d / 5, wd = d % 5;
    int h0 = h / 6, wh = h % 6;
    int w0 = w / 5, ww = w % 5;
    int win = ((b * 8 + d0) * 8 + h0) * 8 + w0;
    return win * 150 + (wd * 6 + wh) * 5 + ww;
}

__device__ __forceinline__ float gelu_f(float u) {
    float u2 = u * u;
    float arg = u * fmaf(0.0713549f, u2, 1.5957691f);
    float e = __expf(arg);
    float r = __builtin_amdgcn_rcpf(e + 1.f);
    return fmaf(-u, r, u);
}

// ---------------------------------------------------------------------------
// K0: weight convert/transpose bf16 [n][k]; fp32 bias matrix [160][160];
// conv weights re-laid to cwT[kk][oc][ci] (ci-contiguous for float4 reads).
// ---------------------------------------------------------------------------
__global__ __launch_bounds__(256) void k_prep_weights(
    const float* __restrict__ wq, const float* __restrict__ wkv,
    const float* __restrict__ w1, const float* __restrict__ w2,
    const float* __restrict__ wproj, const float* __restrict__ relb,
    const float* __restrict__ cw,
    bf16_t* wqT, bf16_t* wkvT, bf16_t* w1T, bf16_t* w2T, bf16_t* wpjT,
    float* bias_mat, float* cwT)
{
    int i = blockIdx.x * 256 + threadIdx.x;
    if (i < 9216)  wqT[i]  = (bf16_t)wq[(i % 96) * 96 + i / 96];
    if (i < 18432) wkvT[i] = (bf16_t)wkv[(i % 96) * 192 + i / 96];
    if (i < 36864) w1T[i]  = (bf16_t)w1[(i % 96) * 384 + i / 96];
    if (i < 36864) w2T[i]  = (bf16_t)w2[(i % 384) * 96 + i / 384];
    if (i < 9216)  wpjT[i] = (bf16_t)wproj[(i % 96) * 96 + i / 96];
    if (i < 25600) {
        int row = i / 160, col = i % 160;
        float v;
        if (col >= 150) v = -1e30f;
        else if (row >= 150) v = 0.f;
        else {
            int wd1 = row / 30, rh1 = row % 30, wh1 = rh1 / 5, ww1 = rh1 % 5;
            int wd2 = col / 30, rh2 = col % 30, wh2 = rh2 / 5, ww2 = rh2 % 5;
            int idx = (wd1 - wd2 + 4) * 99 + (wh1 - wh2 + 5) * 9 + (ww1 - ww2 + 4);
            v = relb[idx];
        }
        bias_mat[i] = v;
    }
    if (i < 7776) {
        int kk = i / 288, rem = i % 288;
        int oc = rem / 96, ci = rem % 96;
        cwT[i] = cw[oc * 2592 + ci * 27 + kk];
    }
}

// ---------------------------------------------------------------------------
// K1: transpose->token order + LayerNorm (bf16 out) + fp32 Im shortcut to x2.
// grid = 3840, 256 threads.
// ---------------------------------------------------------------------------
__global__ __launch_bounds__(256) void k_ln_transpose(
    const float* __restrict__ Im, const float* __restrict__ If,
    const float* __restrict__ g1q, const float* __restrict__ b1q,
    const float* __restrict__ g1k, const float* __restrict__ b1k,
    bf16_t* __restrict__ xln, bf16_t* __restrict__ yln,
    float* __restrict__ x2s)
{
    __shared__ float tile[40 * 97];
    __shared__ float mean_s[40], rstd_s[40];
    int blk = blockIdx.x;
    int b = blk / (40 * 48);
    int rem = blk % (40 * 48);
    int d = rem / 48, h = rem % 48;
    int tid = threadIdx.x;

    for (int pass = 0; pass < 2; ++pass) {
        const float* src = pass ? If : Im;
        const float* gg = pass ? g1k : g1q;
        const float* bb = pass ? b1k : b1q;
        bf16_t* dst = pass ? yln : xln;

        for (int i = tid; i < 96 * 40; i += 256) {
            int c = i / 40, w = i % 40;
            tile[w * 97 + c] = src[(size_t)(b * 96 + c) * 76800 + d * 1920 + h * 40 + w];
        }
        __syncthreads();
        if (tid < 40) {
            float s = 0.f, s2 = 0.f;
            for (int c = 0; c < 96; ++c) {
                float v = tile[tid * 97 + c];
                s += v; s2 += v * v;
            }
            float m = s * (1.f / 96.f);
            float var = s2 * (1.f / 96.f) - m * m;
            mean_s[tid] = m;
            rstd_s[tid] = rsqrtf(var + 1e-5f);
        }
        __syncthreads();
        for (int i = tid; i < 40 * 96; i += 256) {
            int w = i / 96, c = i % 96;
            int tok = tok_index(b, d, h, w);
            float raw = tile[w * 97 + c];
            float v = (raw - mean_s[w]) * rstd_s[w] * gg[c] + bb[c];
            dst[(size_t)tok * 96 + c] = (bf16_t)v;
            if (pass == 0) x2s[(size_t)tok * 96 + c] = raw;   // shortcut
        }
        __syncthreads();
    }
}

// ---------------------------------------------------------------------------
// K2: MFMA projection. WT is [N][96] bf16. N=96 -> qb only.
// N=192 -> n<96 writes kb [t][c]; n>=96 writes vT [win][c][160].
// grid = 2400 (64 tokens/block), 256 threads = 4 waves.
// ---------------------------------------------------------------------------
__global__ __launch_bounds__(256) void k_proj_mfma(
    const bf16_t* __restrict__ X, const bf16_t* __restrict__ WT,
    const float* __restrict__ bias, int N,
    bf16_t* __restrict__ outA, bf16_t* __restrict__ vT)
{
    __shared__ bf16_t xs[64 * 104];
    int tid = threadIdx.x;
    int t0 = blockIdx.x * 64;

    const uint4* xg = (const uint4*)(X + (size_t)t0 * 96);
    uint4* xsv = (uint4*)xs;
    for (int i = tid; i < 768; i += 256) {
        int row = i / 12, c16 = i % 12;
        xsv[row * 13 + c16] = xg[i];
    }
    __syncthreads();

    int w = tid >> 6, l = tid & 63;
    int lm = l & 15, lk = (l >> 4) * 8;
    int m0 = w * 16;
    bf16x8 a[3];
#pragma unroll
    for (int kk = 0; kk < 3; ++kk)
        a[kk] = *(const bf16x8*)(xs + (m0 + lm) * 104 + kk * 32 + lk);

    int trow[4], twin[4], tm[4];
#pragma unroll
    for (int r = 0; r < 4; ++r) {
        int t = t0 + m0 + (l >> 4) * 4 + r;
        trow[r] = t; twin[r] = t / 150; tm[r] = t - twin[r] * 150;
    }

    int ntiles = N >> 4;
    for (int ti = 0; ti < ntiles; ++ti) {
        int n0 = ti * 16;
        f32x4 c = {0.f, 0.f, 0.f, 0.f};
        const bf16_t* wp = WT + (size_t)(n0 + lm) * 96 + lk;
        c = __builtin_amdgcn_mfma_f32_16x16x32_bf16(a[0], *(const bf16x8*)(wp), c, 0, 0, 0);
        c = __builtin_amdgcn_mfma_f32_16x16x32_bf16(a[1], *(const bf16x8*)(wp + 32), c, 0, 0, 0);
        c = __builtin_amdgcn_mfma_f32_16x16x32_bf16(a[2], *(const bf16x8*)(wp + 64), c, 0, 0, 0);
        int n = n0 + lm;
        float bs = bias[n];
        if (n < 96) {
#pragma unroll
            for (int r = 0; r < 4; ++r)
                outA[(size_t)trow[r] * 96 + n] = (bf16_t)(c[r] + bs);
        } else {
            int cc = n - 96;
#pragma unroll
            for (int r = 0; r < 4; ++r)
                vT[((size_t)twin[r] * 96 + cc) * 160 + tm[r]] = (bf16_t)(c[r] + bs);
        }
    }
}

// ---------------------------------------------------------------------------
// K34: MFMA attention. One wave per (window, 32-row slab): grid 5120 x 64.
// ---------------------------------------------------------------------------
__global__ __launch_bounds__(64) void k_attn_mfma(
    const bf16_t* __restrict__ qb, const bf16_t* __restrict__ kb,
    const bf16_t* __restrict__ vT, const bf16_t* __restrict__ wpjT,
    const float* __restrict__ bias_mat, const float* __restrict__ bproj,
    float* __restrict__ x2)
{
    __shared__ __align__(16) bf16_t pls[16 * 168];
    int blk = blockIdx.x;
    int win = blk / 5, slab = blk % 5;
    int l = threadIdx.x;
    int lm = l & 15, lq = l >> 4, lk8 = lq * 8;
    size_t wbase = (size_t)win * 150 * 96;
    size_t vbase = (size_t)win * 96 * 160;

    for (int rt = 0; rt < 2; ++rt) {
        int r0 = slab * 32 + rt * 16;

        bf16x8 aq[3];
#pragma unroll
        for (int kk = 0; kk < 3; ++kk)
            aq[kk] = *(const bf16x8*)(qb + wbase + (size_t)(r0 + lm) * 96 + kk * 32 + lk8);

        f32x4 s[10];
#pragma unroll
        for (int nt = 0; nt < 10; ++nt) {
            f32x4 acc = {0.f, 0.f, 0.f, 0.f};
            const bf16_t* kp = kb + wbase + (size_t)(nt * 16 + lm) * 96 + lk8;
            acc = __builtin_amdgcn_mfma_f32_16x16x32_bf16(aq[0], *(const bf16x8*)(kp), acc, 0, 0, 0);
            acc = __builtin_amdgcn_mfma_f32_16x16x32_bf16(aq[1], *(const bf16x8*)(kp + 32), acc, 0, 0, 0);
            acc = __builtin_amdgcn_mfma_f32_16x16x32_bf16(aq[2], *(const bf16x8*)(kp + 64), acc, 0, 0, 0);
            s[nt] = acc;
        }

#pragma unroll
        for (int r = 0; r < 4; ++r) {
            int grow = r0 + lq * 4 + r;
            float rowmax = -3.0e38f;
#pragma unroll
            for (int nt = 0; nt < 10; ++nt) {
                float bv = bias_mat[grow * 160 + nt * 16 + lm];
                float v = fmaf(s[nt][r], SCALE, bv);
                s[nt][r] = v;
                rowmax = fmaxf(rowmax, v);
            }
            rowmax = fmaxf(rowmax, __shfl_xor(rowmax, 1));
            rowmax = fmaxf(rowmax, __shfl_xor(rowmax, 2));
            rowmax = fmaxf(rowmax, __shfl_xor(rowmax, 4));
            rowmax = fmaxf(rowmax, __shfl_xor(rowmax, 8));
            float ssum = 0.f;
#pragma unroll
            for (int nt = 0; nt < 10; ++nt) {
                float e = __expf(s[nt][r] - rowmax);
                s[nt][r] = e;
                ssum += e;
            }
            ssum += __shfl_xor(ssum, 1);
            ssum += __shfl_xor(ssum, 2);
            ssum += __shfl_xor(ssum, 4);
            ssum += __shfl_xor(ssum, 8);
            float inv = 1.f / ssum;
            int lrow = lq * 4 + r;
#pragma unroll
            for (int nt = 0; nt < 10; ++nt)
                pls[lrow * 168 + nt * 16 + lm] = (bf16_t)(s[nt][r] * inv);
        }
        __syncthreads();

        f32x4 o[6];
#pragma unroll
        for (int ct = 0; ct < 6; ++ct) o[ct] = (f32x4){0.f, 0.f, 0.f, 0.f};
#pragma unroll
        for (int kf = 0; kf < 5; ++kf) {
            bf16x8 ap = *(const bf16x8*)(pls + lm * 168 + kf * 32 + lk8);
#pragma unroll
            for (int ct = 0; ct < 6; ++ct) {
                const bf16_t* vp = vT + vbase + (size_t)(ct * 16 + lm) * 160 + kf * 32 + lk8;
                o[ct] = __builtin_amdgcn_mfma_f32_16x16x32_bf16(ap, *(const bf16x8*)(vp), o[ct], 0, 0, 0);
            }
        }
        __syncthreads();

#pragma unroll
        for (int ct = 0; ct < 6; ++ct)
#pragma unroll
            for (int r = 0; r < 4; ++r)
                pls[(lq * 4 + r) * 104 + ct * 16 + lm] = (bf16_t)o[ct][r];
        __syncthreads();

        bf16x8 ao[3];
#pragma unroll
        for (int kk = 0; kk < 3; ++kk)
            ao[kk] = *(const bf16x8*)(pls + lm * 104 + kk * 32 + lk8);
        f32x4 pj[6];
#pragma unroll
        for (int ct = 0; ct < 6; ++ct) {
            f32x4 acc = {0.f, 0.f, 0.f, 0.f};
            const bf16_t* wp = wpjT + (size_t)(ct * 16 + lm) * 96 + lk8;
            acc = __builtin_amdgcn_mfma_f32_16x16x32_bf16(ao[0], *(const bf16x8*)(wp), acc, 0, 0, 0);
            acc = __builtin_amdgcn_mfma_f32_16x16x32_bf16(ao[1], *(const bf16x8*)(wp + 32), acc, 0, 0, 0);
            acc = __builtin_amdgcn_mfma_f32_16x16x32_bf16(ao[2], *(const bf16x8*)(wp + 64), acc, 0, 0, 0);
            pj[ct] = acc;
        }
#pragma unroll
        for (int r = 0; r < 4; ++r) {
            int gr = r0 + lq * 4 + r;
            if (gr < 150) {
                size_t t = (size_t)win * 150 + gr;
#pragma unroll
                for (int ct = 0; ct < 6; ++ct) {
                    int c = ct * 16 + lm;
                    size_t off = t * 96 + c;
                    x2[off] = x2[off] + pj[ct][r] + bproj[c];
                }
            }
        }
        __syncthreads();
    }
}

// ---------------------------------------------------------------------------
// K5: MFMA MLP. Reads x2 (token order fp32), writes conv input xc as bf16 in
// SPATIAL order (b,d,h,w,c): x3 = x2 + gelu(ln2(x2)@w1+b1)@w2+b2.
// grid = 2400 (64 tokens), 256 threads = 4 waves.
// ---------------------------------------------------------------------------
__global__ __launch_bounds__(256) void k_mlp_mfma(
    const float* __restrict__ x2,
    const float* __restrict__ g2, const float* __restrict__ b2,
    const bf16_t* __restrict__ w1T, const float* __restrict__ b1,
    const bf16_t* __restrict__ w2T, const float* __restrict__ b2v,
    bf16_t* __restrict__ xc)
{
    __shared__ __align__(16) char smem[39424];
    float* xf = (float*)smem;                  // [64][100] fp32 (dies)
    bf16_t* xs = (bf16_t*)(smem + 25600);      // [64][104] bf16 LN'd
    bf16_t* hs = (bf16_t*)smem;                // 4 waves x [16][136] bf16
    float* mrs = (float*)(smem + 38912);

    int tid = threadIdx.x;
    int t0 = blockIdx.x * 64;

    const float4* xg = (const float4*)(x2 + (size_t)t0 * 96);
    for (int i = tid; i < 1536; i += 256) {
        int row = i / 24, c4 = i % 24;
        *(float4*)(xf + row * 100 + c4 * 4) = xg[i];
    }
    __syncthreads();

    {
        int t = tid >> 2, p = tid & 3;
        float s = 0.f, s2 = 0.f;
        const float* rp = xf + t * 100 + p * 24;
#pragma unroll 6
        for (int j = 0; j < 24; ++j) { float v = rp[j]; s += v; s2 += v * v; }
        s += __shfl_xor(s, 1); s += __shfl_xor(s, 2);
        s2 += __shfl_xor(s2, 1); s2 += __shfl_xor(s2, 2);
        if (p == 0) {
            float m = s * (1.f / 96.f);
            float var = s2 * (1.f / 96.f) - m * m;
            mrs[t] = m;
            mrs[64 + t] = rsqrtf(var + 1e-5f);
        }
    }
    __syncthreads();

    for (int i = tid; i < 6144; i += 256) {
        int t = i / 96, c = i % 96;
        float v = (xf[t * 100 + c] - mrs[t]) * mrs[64 + t] * g2[c] + b2[c];
        xs[t * 104 + c] = (bf16_t)v;
    }
    __syncthreads();

    int w = tid >> 6, l = tid & 63;
    int lm = l & 15, lk = (l >> 4) * 8;
    int m0 = w * 16;
    bf16_t* hw = hs + w * 16 * 136;

    bf16x8 a[3];
#pragma unroll
    for (int kk = 0; kk < 3; ++kk)
        a[kk] = *(const bf16x8*)(xs + (m0 + lm) * 104 + kk * 32 + lk);

    f32x4 acc2[6];
#pragma unroll
    for (int i = 0; i < 6; ++i) acc2[i] = (f32x4){0.f, 0.f, 0.f, 0.f};

    for (int cc = 0; cc < 3; ++cc) {
#pragma unroll
        for (int ti = 0; ti < 8; ++ti) {
            int n = cc * 128 + ti * 16 + lm;
            const bf16_t* wp = w1T + (size_t)n * 96 + lk;
            f32x4 c1 = {0.f, 0.f, 0.f, 0.f};
            c1 = __builtin_amdgcn_mfma_f32_16x16x32_bf16(a[0], *(const bf16x8*)(wp), c1, 0, 0, 0);
            c1 = __builtin_amdgcn_mfma_f32_16x16x32_bf16(a[1], *(const bf16x8*)(wp + 32), c1, 0, 0, 0);
            c1 = __builtin_amdgcn_mfma_f32_16x16x32_bf16(a[2], *(const bf16x8*)(wp + 64), c1, 0, 0, 0);
            float bs = b1[n];
#pragma unroll
            for (int r = 0; r < 4; ++r) {
                int row = (l >> 4) * 4 + r;
                hw[row * 136 + ti * 16 + lm] = (bf16_t)gelu_f(c1[r] + bs);
            }
        }
        bf16x8 ha[4];
#pragma unroll
        for (int kk = 0; kk < 4; ++kk)
            ha[kk] = *(const bf16x8*)(hw + lm * 136 + kk * 32 + lk);
#pragma unroll
        for (int ti = 0; ti < 6; ++ti) {
            const bf16_t* wp = w2T + (size_t)(ti * 16 + lm) * 384 + cc * 128 + lk;
#pragma unroll
            for (int kk = 0; kk < 4; ++kk)
                acc2[ti] = __builtin_amdgcn_mfma_f32_16x16x32_bf16(
                    ha[kk], *(const bf16x8*)(wp + kk * 32), acc2[ti], 0, 0, 0);
        }
    }

    // epilogue: residual + bias; write bf16 in spatial order for the conv
    int srow[4];
#pragma unroll
    for (int r = 0; r < 4; ++r) {
        int t = t0 + m0 + (l >> 4) * 4 + r;
        int win = t / 150, nn = t - win * 150;
        int b = win >> 9, d0 = (win >> 6) & 7, h0 = (win >> 3) & 7, w0 = win & 7;
        int wd = nn / 30, rem = nn % 30, wh = rem / 5, ww = rem % 5;
        srow[r] = ((b * 40 + d0 * 5 + wd) * 48 + h0 * 6 + wh) * 40 + w0 * 5 + ww;
    }
#pragma unroll
    for (int ti = 0; ti < 6; ++ti) {
        int n = ti * 16 + lm;
        float bs = b2v[n];
#pragma unroll
        for (int r = 0; r < 4; ++r) {
            int t = t0 + m0 + (l >> 4) * 4 + r;
            size_t o = (size_t)t * 96 + n;
            xc[(size_t)srow[r] * 96 + n] = (bf16_t)(x2[o] + acc2[ti][r] + bs);
        }
    }
}

// ---------------------------------------------------------------------------
// K6: 3x3x3 conv (96 -> 3), zero pad. Input xc: bf16, spatial (b,d,h,w,c).
// Weights cwT[kk][oc][ci] staged in LDS, read as broadcast float4.
// grid = 600, 256 threads (one thread per spatial point, 3 out channels).
// ---------------------------------------------------------------------------
__global__ __launch_bounds__(256) void k_conv(
    const bf16_t* __restrict__ xc, const float* __restrict__ cwT,
    const float* __restrict__ cb, float* __restrict__ out)
{
    __shared__ float wl[7776];   // [kk][oc][ci]
    int tid = threadIdx.x;
    for (int i = tid; i < 7776; i += 256) wl[i] = cwT[i];
    __syncthreads();

    int s = blockIdx.x * 256 + tid;
    int b = s / 76800, r = s % 76800;
    int d = r / 1920, h = (r / 40) % 48, w = r % 40;
    float a0 = 0.f, a1 = 0.f, a2 = 0.f;

    for (int dd = 0; dd < 3; ++dd) {
        int d2 = d + dd - 1;
        if ((unsigned)d2 >= 40u) continue;
        for (int hh = 0; hh < 3; ++hh) {
            int h2 = h + hh - 1;
            if ((unsigned)h2 >= 48u) continue;
            for (int ww = 0; ww < 3; ++ww) {
                int w2 = w + ww - 1;
                if ((unsigned)w2 >= 40u) continue;
                int kk = (dd * 3 + hh) * 3 + ww;
                const bf16x8* xp = (const bf16x8*)
                    (xc + ((size_t)((b * 40 + d2) * 48 + h2) * 40 + w2) * 96);
                const float* wk = wl + kk * 288;
#pragma unroll
                for (int c8 = 0; c8 < 12; ++c8) {
                    bf16x8 xv = xp[c8];
                    float x0 = (float)xv[0], x1 = (float)xv[1];
                    float x2v = (float)xv[2], x3 = (float)xv[3];
                    float x4 = (float)xv[4], x5 = (float)xv[5];
                    float x6 = (float)xv[6], x7 = (float)xv[7];
                    float4 wa0 = *(const float4*)(wk + c8 * 8);
                    float4 wb0 = *(const float4*)(wk + c8 * 8 + 4);
                    float4 wa1 = *(const float4*)(wk + 96 + c8 * 8);
                    float4 wb1 = *(const float4*)(wk + 96 + c8 * 8 + 4);
                    float4 wa2 = *(const float4*)(wk + 192 + c8 * 8);
                    float4 wb2 = *(const float4*)(wk + 192 + c8 * 8 + 4);
                    a0 += x0 * wa0.x + x1 * wa0.y + x2v * wa0.z + x3 * wa0.w
                        + x4 * wb0.x + x5 * wb0.y + x6 * wb0.z + x7 * wb0.w;
                    a1 += x0 * wa1.x + x1 * wa1.y + x2v * wa1.z + x3 * wa1.w
                        + x4 * wb1.x + x5 * wb1.y + x6 * wb1.z + x7 * wb1.w;
                    a2 += x0 * wa2.x + x1 * wa2.y + x2v * wa2.z + x3 * wa2.w
                        + x4 * wb2.x + x5 * wb2.y + x6 * wb2.z + x7 * wb2.w;
                }
            }
        }
    }
    out[(size_t)(b * 3 + 0) * 76800 + r] = a0 + cb[0];
    out[(size_t)(b * 3 + 1) * 76800 + r] = a1 + cb[1];
    out[(size_t)(b * 3 + 2) * 76800 + r] = a2 + cb[2];
}

// ---------------------------------------------------------------------------
extern "C" void kernel_launch(void* const* d_in, const int* in_sizes, int n_in,
                              void* d_out, int out_size, void* d_ws, size_t ws_size,
                              hipStream_t stream)
{
    (void)in_sizes; (void)n_in; (void)out_size;

    const float* Im  = (const float*)d_in[0];
    const float* If  = (const float*)d_in[1];
    const float* g1q = (const float*)d_in[2];
    const float* b1q = (const float*)d_in[3];
    const float* g1k = (const float*)d_in[4];
    const float* b1k = (const float*)d_in[5];
    const float* wq  = (const float*)d_in[6];
    const float* bq  = (const float*)d_in[7];
    const float* wkv = (const float*)d_in[8];
    const float* bkv = (const float*)d_in[9];
    const float* wpj = (const float*)d_in[10];
    const float* bpj = (const float*)d_in[11];
    const float* rb  = (const float*)d_in[12];
    const float* g2  = (const float*)d_in[13];
    const float* b2  = (const float*)d_in[14];
    const float* w1  = (const float*)d_in[15];
    const float* b1  = (const float*)d_in[16];
    const float* w2  = (const float*)d_in[17];
    const float* b2v = (const float*)d_in[18];
    const float* cw  = (const float*)d_in[19];
    const float* cb  = (const float*)d_in[20];
    float* out = (float*)d_out;

    size_t U = (size_t)NTOK * 96;
    if (ws_size < 4 * U * sizeof(float)) return;
    float* ws = (float*)d_ws;
    bf16_t* xlnb = (bf16_t*)ws;                        // U bf16 (-> xc later)
    bf16_t* ylnb = (bf16_t*)(ws + U / 2);              // U bf16
    bf16_t* qb   = (bf16_t*)(ws + U);                  // U bf16
    bf16_t* kb   = (bf16_t*)(ws + 3 * U / 2);          // U bf16
    bf16_t* vT   = (bf16_t*)(ws + 2 * U);              // 1024*96*160 bf16
    float*  wtail = ws + 2 * U + (1024 * 96 * 160) / 2;
    bf16_t* wqT  = (bf16_t*)wtail;                     // 9216
    bf16_t* wkvT = wqT + 9216;                         // 18432
    bf16_t* w1T  = wkvT + 18432;                       // 36864
    bf16_t* w2T  = w1T + 36864;                        // 36864
    bf16_t* wpjT = w2T + 36864;                        // 9216
    float*  bias_mat = (float*)(wpjT + 9216 + 2);      // 25600 fp32
    float*  cwT  = bias_mat + 25600;                   // 7776 fp32
    float*  x2f  = ws + 3 * U;                         // U fp32
    bf16_t* xc   = (bf16_t*)ws;                        // U bf16, spatial order
                                                       // (aliases dead xlnb/yl)

    k_prep_weights<<<144, 256, 0, stream>>>(wq, wkv, w1, w2, wpj, rb, cw,
                                            wqT, wkvT, w1T, w2T, wpjT,
                                            bias_mat, cwT);
    k_ln_transpose<<<3840, 256, 0, stream>>>(Im, If, g1q, b1q, g1k, b1k,
                                             xlnb, ylnb, x2f);
    k_proj_mfma<<<2400, 256, 0, stream>>>(xlnb, wqT, bq, 96, qb, nullptr);
    k_proj_mfma<<<2400, 256, 0, stream>>>(ylnb, wkvT, bkv, 192, kb, vT);
    k_attn_mfma<<<5120, 64, 0, stream>>>(qb, kb, vT, wpjT, bias_mat, bpj, x2f);
    k_mlp_mfma<<<2400, 256, 0, stream>>>(x2f, g2, b2, w1T, b1, w2T, b2v, xc);
    k_conv<<<600, 256, 0, stream>>>(xc, cwT, cb, out);
}

// Round 5
// 734.335 us; speedup vs baseline: 2.6727x; 1.1244x over previous
//
#include <hip/hip_runtime.h>
#include <math.h>

// ---------------------------------------------------------------------------
// Swin-3D cross-attention block. Round 4: latency-bound attention fixed by
// per-window blocks (6 waves) with K staged in LDS (m97-style staging).
// Token order = window-partitioned:
//   win = ((b*8 + d/5)*8 + h/6)*8 + w/5 ; t = ((d%5)*6 + h%6)*5 + w%5
// Workspace layout (fp32 offsets, U = 153600*96 = 14,745,600):
//   [0,U/2)   xlnb bf16   --later reused as-> xc bf16 (spatial-order conv in)
//   [U/2,U)   ylnb bf16
//   [U,1.5U)  qb bf16     [1.5U,2U) kb bf16
//   [2U,+7.86M) vT bf16 [win][96][160]
//   then bf16 weights wqT|wkvT|w1T|w2T|wpjT, fp32 bias_mat[160][160], cwT
//   [3U,4U)   x2 fp32 (K1 writes Im shortcut; attn accumulates in place)
// ---------------------------------------------------------------------------

static constexpr int NTOK = 153600;
static constexpr float SCALE = 0.10206207261596575f; // 96^-0.5

typedef __bf16 bf16_t;
typedef __bf16 bf16x8 __attribute__((ext_vector_type(8)));
typedef float f32x4 __attribute__((ext_vector_type(4)));

__device__ __forceinline__ int tok_index(int b, int d, int h, int w) {
    int d0 = d / 5, wd = d % 5;
    int h0 = h / 6, wh = h % 6;
    int w0 = w / 5, ww = w % 5;
    int win = ((b * 8 + d0) * 8 + h0) * 8 + w0;
    return win * 150 + (wd * 6 + wh) * 5 + ww;
}

__device__ __forceinline__ float gelu_f(float u) {
    float u2 = u * u;
    float arg = u * fmaf(0.0713549f, u2, 1.5957691f);
    float e = __expf(arg);
    float r = __builtin_amdgcn_rcpf(e + 1.f);
    return fmaf(-u, r, u);
}

// ---------------------------------------------------------------------------
// K0: weight convert/transpose bf16 [n][k]; fp32 bias matrix [160][160];
// conv weights re-laid to cwT[kk][oc][ci] (ci-contiguous for float4 reads).
// ---------------------------------------------------------------------------
__global__ __launch_bounds__(256) void k_prep_weights(
    const float* __restrict__ wq, const float* __restrict__ wkv,
    const float* __restrict__ w1, const float* __restrict__ w2,
    const float* __restrict__ wproj, const float* __restrict__ relb,
    const float* __restrict__ cw,
    bf16_t* wqT, bf16_t* wkvT, bf16_t* w1T, bf16_t* w2T, bf16_t* wpjT,
    float* bias_mat, float* cwT)
{
    int i = blockIdx.x * 256 + threadIdx.x;
    if (i < 9216)  wqT[i]  = (bf16_t)wq[(i % 96) * 96 + i / 96];
    if (i < 18432) wkvT[i] = (bf16_t)wkv[(i % 96) * 192 + i / 96];
    if (i < 36864) w1T[i]  = (bf16_t)w1[(i % 96) * 384 + i / 96];
    if (i < 36864) w2T[i]  = (bf16_t)w2[(i % 384) * 96 + i / 384];
    if (i < 9216)  wpjT[i] = (bf16_t)wproj[(i % 96) * 96 + i / 96];
    if (i < 25600) {
        int row = i / 160, col = i % 160;
        float v;
        if (col >= 150) v = -1e30f;
        else if (row >= 150) v = 0.f;
        else {
            int wd1 = row / 30, rh1 = row % 30, wh1 = rh1 / 5, ww1 = rh1 % 5;
            int wd2 = col / 30, rh2 = col % 30, wh2 = rh2 / 5, ww2 = rh2 % 5;
            int idx = (wd1 - wd2 + 4) * 99 + (wh1 - wh2 + 5) * 9 + (ww1 - ww2 + 4);
            v = relb[idx];
        }
        bias_mat[i] = v;
    }
    if (i < 7776) {
        int kk = i / 288, rem = i % 288;
        int oc = rem / 96, ci = rem % 96;
        cwT[i] = cw[oc * 2592 + ci * 27 + kk];
    }
}

// ---------------------------------------------------------------------------
// K1: transpose->token order + LayerNorm (bf16 out) + fp32 Im shortcut to x2.
// grid = 3840, 256 threads.
// ---------------------------------------------------------------------------
__global__ __launch_bounds__(256) void k_ln_transpose(
    const float* __restrict__ Im, const float* __restrict__ If,
    const float* __restrict__ g1q, const float* __restrict__ b1q,
    const float* __restrict__ g1k, const float* __restrict__ b1k,
    bf16_t* __restrict__ xln, bf16_t* __restrict__ yln,
    float* __restrict__ x2s)
{
    __shared__ float tile[40 * 97];
    __shared__ float mean_s[40], rstd_s[40];
    int blk = blockIdx.x;
    int b = blk / (40 * 48);
    int rem = blk % (40 * 48);
    int d = rem / 48, h = rem % 48;
    int tid = threadIdx.x;

    for (int pass = 0; pass < 2; ++pass) {
        const float* src = pass ? If : Im;
        const float* gg = pass ? g1k : g1q;
        const float* bb = pass ? b1k : b1q;
        bf16_t* dst = pass ? yln : xln;

        for (int i = tid; i < 96 * 40; i += 256) {
            int c = i / 40, w = i % 40;
            tile[w * 97 + c] = src[(size_t)(b * 96 + c) * 76800 + d * 1920 + h * 40 + w];
        }
        __syncthreads();
        if (tid < 40) {
            float s = 0.f, s2 = 0.f;
            for (int c = 0; c < 96; ++c) {
                float v = tile[tid * 97 + c];
                s += v; s2 += v * v;
            }
            float m = s * (1.f / 96.f);
            float var = s2 * (1.f / 96.f) - m * m;
            mean_s[tid] = m;
            rstd_s[tid] = rsqrtf(var + 1e-5f);
        }
        __syncthreads();
        for (int i = tid; i < 40 * 96; i += 256) {
            int w = i / 96, c = i % 96;
            int tok = tok_index(b, d, h, w);
            float raw = tile[w * 97 + c];
            float v = (raw - mean_s[w]) * rstd_s[w] * gg[c] + bb[c];
            dst[(size_t)tok * 96 + c] = (bf16_t)v;
            if (pass == 0) x2s[(size_t)tok * 96 + c] = raw;   // shortcut
        }
        __syncthreads();
    }
}

// ---------------------------------------------------------------------------
// K2: MFMA projection. WT is [N][96] bf16. N=96 -> qb only.
// N=192 -> n<96 writes kb [t][c]; n>=96 writes vT [win][c][160].
// grid = 2400 (64 tokens/block), 256 threads = 4 waves.
// ---------------------------------------------------------------------------
__global__ __launch_bounds__(256) void k_proj_mfma(
    const bf16_t* __restrict__ X, const bf16_t* __restrict__ WT,
    const float* __restrict__ bias, int N,
    bf16_t* __restrict__ outA, bf16_t* __restrict__ vT)
{
    __shared__ bf16_t xs[64 * 104];
    int tid = threadIdx.x;
    int t0 = blockIdx.x * 64;

    const uint4* xg = (const uint4*)(X + (size_t)t0 * 96);
    uint4* xsv = (uint4*)xs;
    for (int i = tid; i < 768; i += 256) {
        int row = i / 12, c16 = i % 12;
        xsv[row * 13 + c16] = xg[i];
    }
    __syncthreads();

    int w = tid >> 6, l = tid & 63;
    int lm = l & 15, lk = (l >> 4) * 8;
    int m0 = w * 16;
    bf16x8 a[3];
#pragma unroll
    for (int kk = 0; kk < 3; ++kk)
        a[kk] = *(const bf16x8*)(xs + (m0 + lm) * 104 + kk * 32 + lk);

    int trow[4], twin[4], tm[4];
#pragma unroll
    for (int r = 0; r < 4; ++r) {
        int t = t0 + m0 + (l >> 4) * 4 + r;
        trow[r] = t; twin[r] = t / 150; tm[r] = t - twin[r] * 150;
    }

    int ntiles = N >> 4;
    for (int ti = 0; ti < ntiles; ++ti) {
        int n0 = ti * 16;
        f32x4 c = {0.f, 0.f, 0.f, 0.f};
        const bf16_t* wp = WT + (size_t)(n0 + lm) * 96 + lk;
        c = __builtin_amdgcn_mfma_f32_16x16x32_bf16(a[0], *(const bf16x8*)(wp), c, 0, 0, 0);
        c = __builtin_amdgcn_mfma_f32_16x16x32_bf16(a[1], *(const bf16x8*)(wp + 32), c, 0, 0, 0);
        c = __builtin_amdgcn_mfma_f32_16x16x32_bf16(a[2], *(const bf16x8*)(wp + 64), c, 0, 0, 0);
        int n = n0 + lm;
        float bs = bias[n];
        if (n < 96) {
#pragma unroll
            for (int r = 0; r < 4; ++r)
                outA[(size_t)trow[r] * 96 + n] = (bf16_t)(c[r] + bs);
        } else {
            int cc = n - 96;
#pragma unroll
            for (int r = 0; r < 4; ++r)
                vT[((size_t)twin[r] * 96 + cc) * 160 + tm[r]] = (bf16_t)(c[r] + bs);
        }
    }
}

// ---------------------------------------------------------------------------
// K34: MFMA attention, one block (6 waves) per window. K staged in LDS once
// ([160][104] bf16, rows>=150 zeroed); each wave owns row-tiles wv, wv+6.
// P/O round-trip through per-wave LDS scratch [16][164]. V and wproj B-frags
// straight from global (L2-hot). x2 += O@wprojT + bproj (shortcut pre-added).
// LDS: 33280 + 6*5248 = 64768 B -> 2 blocks/CU = 12 waves/CU.
// ---------------------------------------------------------------------------
__global__ __launch_bounds__(384) void k_attn_mfma(
    const bf16_t* __restrict__ qb, const bf16_t* __restrict__ kb,
    const bf16_t* __restrict__ vT, const bf16_t* __restrict__ wpjT,
    const float* __restrict__ bias_mat, const float* __restrict__ bproj,
    float* __restrict__ x2)
{
    __shared__ __align__(16) bf16_t kls[160 * 104];        // 33280 B
    __shared__ __align__(16) bf16_t pls_all[6 * 16 * 164]; // 31488 B
    int win = blockIdx.x;
    int tid = threadIdx.x;
    int wv = tid >> 6, l = tid & 63;
    int lm = l & 15, lq = l >> 4, lk8 = lq * 8;
    size_t wbase = (size_t)win * 150 * 96;
    size_t vbase = (size_t)win * 96 * 160;
    bf16_t* pls = pls_all + wv * 16 * 164;

    // ---- stage K into LDS (coalesced 16B chunks), zero pad rows 150..159 ----
    {
        const uint4* src = (const uint4*)(kb + wbase);   // 150 rows x 12 chunks
        for (int i = tid; i < 1800; i += 384) {
            int row = i / 12, c = i % 12;
            *(uint4*)(kls + row * 104 + c * 8) = src[i];
        }
        uint4 z = {0, 0, 0, 0};
        for (int i = tid; i < 130; i += 384) {           // 10 rows x 13 chunks
            int row = 150 + i / 13, c = i % 13;
            *(uint4*)(kls + row * 104 + c * 8) = z;
        }
    }
    __syncthreads();

    for (int ti = wv; ti < 10; ti += 6) {
        int r0 = ti * 16;

        // ---- S = Q K^T (Q A-frags from global, K B-frags from LDS) ----
        bf16x8 aq[3];
#pragma unroll
        for (int kk = 0; kk < 3; ++kk)
            aq[kk] = *(const bf16x8*)(qb + wbase + (size_t)(r0 + lm) * 96 + kk * 32 + lk8);

        f32x4 s[10];
#pragma unroll
        for (int nt = 0; nt < 10; ++nt) {
            f32x4 acc = {0.f, 0.f, 0.f, 0.f};
            const bf16_t* kp = kls + (nt * 16 + lm) * 104 + lk8;
            acc = __builtin_amdgcn_mfma_f32_16x16x32_bf16(aq[0], *(const bf16x8*)(kp), acc, 0, 0, 0);
            acc = __builtin_amdgcn_mfma_f32_16x16x32_bf16(aq[1], *(const bf16x8*)(kp + 32), acc, 0, 0, 0);
            acc = __builtin_amdgcn_mfma_f32_16x16x32_bf16(aq[2], *(const bf16x8*)(kp + 64), acc, 0, 0, 0);
            s[nt] = acc;
        }

        // ---- softmax (bias+mask folded into bias_mat) ----
#pragma unroll
        for (int r = 0; r < 4; ++r) {
            int grow = r0 + lq * 4 + r;
            float rowmax = -3.0e38f;
#pragma unroll
            for (int nt = 0; nt < 10; ++nt) {
                float bv = bias_mat[grow * 160 + nt * 16 + lm];
                float v = fmaf(s[nt][r], SCALE, bv);
                s[nt][r] = v;
                rowmax = fmaxf(rowmax, v);
            }
            rowmax = fmaxf(rowmax, __shfl_xor(rowmax, 1));
            rowmax = fmaxf(rowmax, __shfl_xor(rowmax, 2));
            rowmax = fmaxf(rowmax, __shfl_xor(rowmax, 4));
            rowmax = fmaxf(rowmax, __shfl_xor(rowmax, 8));
            float ssum = 0.f;
#pragma unroll
            for (int nt = 0; nt < 10; ++nt) {
                float e = __expf(s[nt][r] - rowmax);
                s[nt][r] = e;
                ssum += e;
            }
            ssum += __shfl_xor(ssum, 1);
            ssum += __shfl_xor(ssum, 2);
            ssum += __shfl_xor(ssum, 4);
            ssum += __shfl_xor(ssum, 8);
            float inv = 1.f / ssum;
            int lrow = lq * 4 + r;
#pragma unroll
            for (int nt = 0; nt < 10; ++nt)
                pls[lrow * 164 + nt * 16 + lm] = (bf16_t)(s[nt][r] * inv);
        }
        // wave-private LDS: no barrier needed (lgkmcnt orders within wave)

        // ---- O = P @ V (P A-frags from LDS, V B-frags from global) ----
        f32x4 o[6];
#pragma unroll
        for (int ct = 0; ct < 6; ++ct) o[ct] = (f32x4){0.f, 0.f, 0.f, 0.f};
#pragma unroll
        for (int kf = 0; kf < 5; ++kf) {
            bf16x8 ap = *(const bf16x8*)(pls + lm * 164 + kf * 32 + lk8);
#pragma unroll
            for (int ct = 0; ct < 6; ++ct) {
                const bf16_t* vp = vT + vbase + (size_t)(ct * 16 + lm) * 160 + kf * 32 + lk8;
                o[ct] = __builtin_amdgcn_mfma_f32_16x16x32_bf16(ap, *(const bf16x8*)(vp), o[ct], 0, 0, 0);
            }
        }

        // ---- O -> LDS (A-layout staging), reuse pls as [16][104] ----
#pragma unroll
        for (int ct = 0; ct < 6; ++ct)
#pragma unroll
            for (int r = 0; r < 4; ++r)
                pls[(lq * 4 + r) * 104 + ct * 16 + lm] = (bf16_t)o[ct][r];

        // ---- x2 += O @ wprojT + bproj ----
        bf16x8 ao[3];
#pragma unroll
        for (int kk = 0; kk < 3; ++kk)
            ao[kk] = *(const bf16x8*)(pls + lm * 104 + kk * 32 + lk8);
        f32x4 pj[6];
#pragma unroll
        for (int ct = 0; ct < 6; ++ct) {
            f32x4 acc = {0.f, 0.f, 0.f, 0.f};
            const bf16_t* wp = wpjT + (size_t)(ct * 16 + lm) * 96 + lk8;
            acc = __builtin_amdgcn_mfma_f32_16x16x32_bf16(ao[0], *(const bf16x8*)(wp), acc, 0, 0, 0);
            acc = __builtin_amdgcn_mfma_f32_16x16x32_bf16(ao[1], *(const bf16x8*)(wp + 32), acc, 0, 0, 0);
            acc = __builtin_amdgcn_mfma_f32_16x16x32_bf16(ao[2], *(const bf16x8*)(wp + 64), acc, 0, 0, 0);
            pj[ct] = acc;
        }
#pragma unroll
        for (int r = 0; r < 4; ++r) {
            int gr = r0 + lq * 4 + r;
            if (gr < 150) {
                size_t t = (size_t)win * 150 + gr;
#pragma unroll
                for (int ct = 0; ct < 6; ++ct) {
                    int c = ct * 16 + lm;
                    size_t off = t * 96 + c;
                    x2[off] = x2[off] + pj[ct][r] + bproj[c];
                }
            }
        }
    }
}

// ---------------------------------------------------------------------------
// K5: MFMA MLP. Reads x2 (token order fp32), writes conv input xc as bf16 in
// SPATIAL order (b,d,h,w,c): x3 = x2 + gelu(ln2(x2)@w1+b1)@w2+b2.
// grid = 2400 (64 tokens), 256 threads = 4 waves.
// ---------------------------------------------------------------------------
__global__ __launch_bounds__(256) void k_mlp_mfma(
    const float* __restrict__ x2,
    const float* __restrict__ g2, const float* __restrict__ b2,
    const bf16_t* __restrict__ w1T, const float* __restrict__ b1,
    const bf16_t* __restrict__ w2T, const float* __restrict__ b2v,
    bf16_t* __restrict__ xc)
{
    __shared__ __align__(16) char smem[39424];
    float* xf = (float*)smem;                  // [64][100] fp32 (dies)
    bf16_t* xs = (bf16_t*)(smem + 25600);      // [64][104] bf16 LN'd
    bf16_t* hs = (bf16_t*)smem;                // 4 waves x [16][136] bf16
    float* mrs = (float*)(smem + 38912);

    int tid = threadIdx.x;
    int t0 = blockIdx.x * 64;

    const float4* xg = (const float4*)(x2 + (size_t)t0 * 96);
    for (int i = tid; i < 1536; i += 256) {
        int row = i / 24, c4 = i % 24;
        *(float4*)(xf + row * 100 + c4 * 4) = xg[i];
    }
    __syncthreads();

    {
        int t = tid >> 2, p = tid & 3;
        float s = 0.f, s2 = 0.f;
        const float* rp = xf + t * 100 + p * 24;
#pragma unroll 6
        for (int j = 0; j < 24; ++j) { float v = rp[j]; s += v; s2 += v * v; }
        s += __shfl_xor(s, 1); s += __shfl_xor(s, 2);
        s2 += __shfl_xor(s2, 1); s2 += __shfl_xor(s2, 2);
        if (p == 0) {
            float m = s * (1.f / 96.f);
            float var = s2 * (1.f / 96.f) - m * m;
            mrs[t] = m;
            mrs[64 + t] = rsqrtf(var + 1e-5f);
        }
    }
    __syncthreads();

    for (int i = tid; i < 6144; i += 256) {
        int t = i / 96, c = i % 96;
        float v = (xf[t * 100 + c] - mrs[t]) * mrs[64 + t] * g2[c] + b2[c];
        xs[t * 104 + c] = (bf16_t)v;
    }
    __syncthreads();

    int w = tid >> 6, l = tid & 63;
    int lm = l & 15, lk = (l >> 4) * 8;
    int m0 = w * 16;
    bf16_t* hw = hs + w * 16 * 136;

    bf16x8 a[3];
#pragma unroll
    for (int kk = 0; kk < 3; ++kk)
        a[kk] = *(const bf16x8*)(xs + (m0 + lm) * 104 + kk * 32 + lk);

    f32x4 acc2[6];
#pragma unroll
    for (int i = 0; i < 6; ++i) acc2[i] = (f32x4){0.f, 0.f, 0.f, 0.f};

    for (int cc = 0; cc < 3; ++cc) {
#pragma unroll
        for (int ti = 0; ti < 8; ++ti) {
            int n = cc * 128 + ti * 16 + lm;
            const bf16_t* wp = w1T + (size_t)n * 96 + lk;
            f32x4 c1 = {0.f, 0.f, 0.f, 0.f};
            c1 = __builtin_amdgcn_mfma_f32_16x16x32_bf16(a[0], *(const bf16x8*)(wp), c1, 0, 0, 0);
            c1 = __builtin_amdgcn_mfma_f32_16x16x32_bf16(a[1], *(const bf16x8*)(wp + 32), c1, 0, 0, 0);
            c1 = __builtin_amdgcn_mfma_f32_16x16x32_bf16(a[2], *(const bf16x8*)(wp + 64), c1, 0, 0, 0);
            float bs = b1[n];
#pragma unroll
            for (int r = 0; r < 4; ++r) {
                int row = (l >> 4) * 4 + r;
                hw[row * 136 + ti * 16 + lm] = (bf16_t)gelu_f(c1[r] + bs);
            }
        }
        bf16x8 ha[4];
#pragma unroll
        for (int kk = 0; kk < 4; ++kk)
            ha[kk] = *(const bf16x8*)(hw + lm * 136 + kk * 32 + lk);
#pragma unroll
        for (int ti = 0; ti < 6; ++ti) {
            const bf16_t* wp = w2T + (size_t)(ti * 16 + lm) * 384 + cc * 128 + lk;
#pragma unroll
            for (int kk = 0; kk < 4; ++kk)
                acc2[ti] = __builtin_amdgcn_mfma_f32_16x16x32_bf16(
                    ha[kk], *(const bf16x8*)(wp + kk * 32), acc2[ti], 0, 0, 0);
        }
    }

    // epilogue: residual + bias; write bf16 in spatial order for the conv
    int srow[4];
#pragma unroll
    for (int r = 0; r < 4; ++r) {
        int t = t0 + m0 + (l >> 4) * 4 + r;
        int win = t / 150, nn = t - win * 150;
        int b = win >> 9, d0 = (win >> 6) & 7, h0 = (win >> 3) & 7, w0 = win & 7;
        int wd = nn / 30, rem = nn % 30, wh = rem / 5, ww = rem % 5;
        srow[r] = ((b * 40 + d0 * 5 + wd) * 48 + h0 * 6 + wh) * 40 + w0 * 5 + ww;
    }
#pragma unroll
    for (int ti = 0; ti < 6; ++ti) {
        int n = ti * 16 + lm;
        float bs = b2v[n];
#pragma unroll
        for (int r = 0; r < 4; ++r) {
            int t = t0 + m0 + (l >> 4) * 4 + r;
            size_t o = (size_t)t * 96 + n;
            xc[(size_t)srow[r] * 96 + n] = (bf16_t)(x2[o] + acc2[ti][r] + bs);
        }
    }
}

// ---------------------------------------------------------------------------
// K6: 3x3x3 conv (96 -> 3), zero pad. Input xc: bf16, spatial (b,d,h,w,c).
// Weights cwT[kk][oc][ci] staged in LDS, read as broadcast float4.
// grid = 600, 256 threads (one thread per spatial point, 3 out channels).
// ---------------------------------------------------------------------------
__global__ __launch_bounds__(256) void k_conv(
    const bf16_t* __restrict__ xc, const float* __restrict__ cwT,
    const float* __restrict__ cb, float* __restrict__ out)
{
    __shared__ float wl[7776];   // [kk][oc][ci]
    int tid = threadIdx.x;
    for (int i = tid; i < 7776; i += 256) wl[i] = cwT[i];
    __syncthreads();

    int s = blockIdx.x * 256 + tid;
    int b = s / 76800, r = s % 76800;
    int d = r / 1920, h = (r / 40) % 48, w = r % 40;
    float a0 = 0.f, a1 = 0.f, a2 = 0.f;

    for (int dd = 0; dd < 3; ++dd) {
        int d2 = d + dd - 1;
        if ((unsigned)d2 >= 40u) continue;
        for (int hh = 0; hh < 3; ++hh) {
            int h2 = h + hh - 1;
            if ((unsigned)h2 >= 48u) continue;
            for (int ww = 0; ww < 3; ++ww) {
                int w2 = w + ww - 1;
                if ((unsigned)w2 >= 40u) continue;
                int kk = (dd * 3 + hh) * 3 + ww;
                const bf16x8* xp = (const bf16x8*)
                    (xc + ((size_t)((b * 40 + d2) * 48 + h2) * 40 + w2) * 96);
                const float* wk = wl + kk * 288;
#pragma unroll
                for (int c8 = 0; c8 < 12; ++c8) {
                    bf16x8 xv = xp[c8];
                    float x0 = (float)xv[0], x1 = (float)xv[1];
                    float x2v = (float)xv[2], x3 = (float)xv[3];
                    float x4 = (float)xv[4], x5 = (float)xv[5];
                    float x6 = (float)xv[6], x7 = (float)xv[7];
                    float4 wa0 = *(const float4*)(wk + c8 * 8);
                    float4 wb0 = *(const float4*)(wk + c8 * 8 + 4);
                    float4 wa1 = *(const float4*)(wk + 96 + c8 * 8);
                    float4 wb1 = *(const float4*)(wk + 96 + c8 * 8 + 4);
                    float4 wa2 = *(const float4*)(wk + 192 + c8 * 8);
                    float4 wb2 = *(const float4*)(wk + 192 + c8 * 8 + 4);
                    a0 += x0 * wa0.x + x1 * wa0.y + x2v * wa0.z + x3 * wa0.w
                        + x4 * wb0.x + x5 * wb0.y + x6 * wb0.z + x7 * wb0.w;
                    a1 += x0 * wa1.x + x1 * wa1.y + x2v * wa1.z + x3 * wa1.w
                        + x4 * wb1.x + x5 * wb1.y + x6 * wb1.z + x7 * wb1.w;
                    a2 += x0 * wa2.x + x1 * wa2.y + x2v * wa2.z + x3 * wa2.w
                        + x4 * wb2.x + x5 * wb2.y + x6 * wb2.z + x7 * wb2.w;
                }
            }
        }
    }
    out[(size_t)(b * 3 + 0) * 76800 + r] = a0 + cb[0];
    out[(size_t)(b * 3 + 1) * 76800 + r] = a1 + cb[1];
    out[(size_t)(b * 3 + 2) * 76800 + r] = a2 + cb[2];
}

// ---------------------------------------------------------------------------
extern "C" void kernel_launch(void* const* d_in, const int* in_sizes, int n_in,
                              void* d_out, int out_size, void* d_ws, size_t ws_size,
                              hipStream_t stream)
{
    (void)in_sizes; (void)n_in; (void)out_size;

    const float* Im  = (const float*)d_in[0];
    const float* If  = (const float*)d_in[1];
    const float* g1q = (const float*)d_in[2];
    const float* b1q = (const float*)d_in[3];
    const float* g1k = (const float*)d_in[4];
    const float* b1k = (const float*)d_in[5];
    const float* wq  = (const float*)d_in[6];
    const float* bq  = (const float*)d_in[7];
    const float* wkv = (const float*)d_in[8];
    const float* bkv = (const float*)d_in[9];
    const float* wpj = (const float*)d_in[10];
    const float* bpj = (const float*)d_in[11];
    const float* rb  = (const float*)d_in[12];
    const float* g2  = (const float*)d_in[13];
    const float* b2  = (const float*)d_in[14];
    const float* w1  = (const float*)d_in[15];
    const float* b1  = (const float*)d_in[16];
    const float* w2  = (const float*)d_in[17];
    const float* b2v = (const float*)d_in[18];
    const float* cw  = (const float*)d_in[19];
    const float* cb  = (const float*)d_in[20];
    float* out = (float*)d_out;

    size_t U = (size_t)NTOK * 96;
    if (ws_size < 4 * U * sizeof(float)) return;
    float* ws = (float*)d_ws;
    bf16_t* xlnb = (bf16_t*)ws;                        // U bf16 (-> xc later)
    bf16_t* ylnb = (bf16_t*)(ws + U / 2);              // U bf16
    bf16_t* qb   = (bf16_t*)(ws + U);                  // U bf16
    bf16_t* kb   = (bf16_t*)(ws + 3 * U / 2);          // U bf16
    bf16_t* vT   = (bf16_t*)(ws + 2 * U);              // 1024*96*160 bf16
    float*  wtail = ws + 2 * U + (1024 * 96 * 160) / 2;
    bf16_t* wqT  = (bf16_t*)wtail;                     // 9216
    bf16_t* wkvT = wqT + 9216;                         // 18432
    bf16_t* w1T  = wkvT + 18432;                       // 36864
    bf16_t* w2T  = w1T + 36864;                        // 36864
    bf16_t* wpjT = w2T + 36864;                        // 9216
    float*  bias_mat = (float*)(wpjT + 9216 + 2);      // 25600 fp32
    float*  cwT  = bias_mat + 25600;                   // 7776 fp32
    float*  x2f  = ws + 3 * U;                         // U fp32
    bf16_t* xc   = (bf16_t*)ws;                        // U bf16, spatial order
                                                       // (aliases dead xlnb/yl)

    k_prep_weights<<<144, 256, 0, stream>>>(wq, wkv, w1, w2, wpj, rb, cw,
                                            wqT, wkvT, w1T, w2T, wpjT,
                                            bias_mat, cwT);
    k_ln_transpose<<<3840, 256, 0, stream>>>(Im, If, g1q, b1q, g1k, b1k,
                                             xlnb, ylnb, x2f);
    k_proj_mfma<<<2400, 256, 0, stream>>>(xlnb, wqT, bq, 96, qb, nullptr);
    k_proj_mfma<<<2400, 256, 0, stream>>>(ylnb, wkvT, bkv, 192, kb, vT);
    k_attn_mfma<<<1024, 384, 0, stream>>>(qb, kb, vT, wpjT, bias_mat, bpj, x2f);
    k_mlp_mfma<<<2400, 256, 0, stream>>>(x2f, g2, b2, w1T, b1, w2T, b2v, xc);
    k_conv<<<600, 256, 0, stream>>>(xc, cwT, cb, out);
}

// Round 6
// 712.358 us; speedup vs baseline: 2.7552x; 1.0309x over previous
//
#include <hip/hip_runtime.h>
#include <math.h>

// ---------------------------------------------------------------------------
// Swin-3D cross-attention block. Round 5: k_mlp occupancy fix — LayerNorm in
// registers (kills the 25.6KB fp32 LDS staging tile), LDS 39.4->30.7 KB ->
// 5 blocks/CU (was 3). Everything else unchanged from round 4.
// Token order = window-partitioned:
//   win = ((b*8 + d/5)*8 + h/6)*8 + w/5 ; t = ((d%5)*6 + h%6)*5 + w%5
// ---------------------------------------------------------------------------

static constexpr int NTOK = 153600;
static constexpr float SCALE = 0.10206207261596575f; // 96^-0.5

typedef __bf16 bf16_t;
typedef __bf16 bf16x8 __attribute__((ext_vector_type(8)));
typedef float f32x4 __attribute__((ext_vector_type(4)));

__device__ __forceinline__ int tok_index(int b, int d, int h, int w) {
    int d0 = d / 5, wd = d % 5;
    int h0 = h / 6, wh = h % 6;
    int w0 = w / 5, ww = w % 5;
    int win = ((b * 8 + d0) * 8 + h0) * 8 + w0;
    return win * 150 + (wd * 6 + wh) * 5 + ww;
}

__device__ __forceinline__ float gelu_f(float u) {
    float u2 = u * u;
    float arg = u * fmaf(0.0713549f, u2, 1.5957691f);
    float e = __expf(arg);
    float r = __builtin_amdgcn_rcpf(e + 1.f);
    return fmaf(-u, r, u);
}

// ---------------------------------------------------------------------------
// K0: weight convert/transpose bf16 [n][k]; fp32 bias matrix [160][160];
// conv weights re-laid to cwT[kk][oc][ci] (ci-contiguous for float4 reads).
// ---------------------------------------------------------------------------
__global__ __launch_bounds__(256) void k_prep_weights(
    const float* __restrict__ wq, const float* __restrict__ wkv,
    const float* __restrict__ w1, const float* __restrict__ w2,
    const float* __restrict__ wproj, const float* __restrict__ relb,
    const float* __restrict__ cw,
    bf16_t* wqT, bf16_t* wkvT, bf16_t* w1T, bf16_t* w2T, bf16_t* wpjT,
    float* bias_mat, float* cwT)
{
    int i = blockIdx.x * 256 + threadIdx.x;
    if (i < 9216)  wqT[i]  = (bf16_t)wq[(i % 96) * 96 + i / 96];
    if (i < 18432) wkvT[i] = (bf16_t)wkv[(i % 96) * 192 + i / 96];
    if (i < 36864) w1T[i]  = (bf16_t)w1[(i % 96) * 384 + i / 96];
    if (i < 36864) w2T[i]  = (bf16_t)w2[(i % 384) * 96 + i / 384];
    if (i < 9216)  wpjT[i] = (bf16_t)wproj[(i % 96) * 96 + i / 96];
    if (i < 25600) {
        int row = i / 160, col = i % 160;
        float v;
        if (col >= 150) v = -1e30f;
        else if (row >= 150) v = 0.f;
        else {
            int wd1 = row / 30, rh1 = row % 30, wh1 = rh1 / 5, ww1 = rh1 % 5;
            int wd2 = col / 30, rh2 = col % 30, wh2 = rh2 / 5, ww2 = rh2 % 5;
            int idx = (wd1 - wd2 + 4) * 99 + (wh1 - wh2 + 5) * 9 + (ww1 - ww2 + 4);
            v = relb[idx];
        }
        bias_mat[i] = v;
    }
    if (i < 7776) {
        int kk = i / 288, rem = i % 288;
        int oc = rem / 96, ci = rem % 96;
        cwT[i] = cw[oc * 2592 + ci * 27 + kk];
    }
}

// ---------------------------------------------------------------------------
// K1: transpose->token order + LayerNorm (bf16 out) + fp32 Im shortcut to x2.
// grid = 3840, 256 threads.
// ---------------------------------------------------------------------------
__global__ __launch_bounds__(256) void k_ln_transpose(
    const float* __restrict__ Im, const float* __restrict__ If,
    const float* __restrict__ g1q, const float* __restrict__ b1q,
    const float* __restrict__ g1k, const float* __restrict__ b1k,
    bf16_t* __restrict__ xln, bf16_t* __restrict__ yln,
    float* __restrict__ x2s)
{
    __shared__ float tile[40 * 97];
    __shared__ float mean_s[40], rstd_s[40];
    int blk = blockIdx.x;
    int b = blk / (40 * 48);
    int rem = blk % (40 * 48);
    int d = rem / 48, h = rem % 48;
    int tid = threadIdx.x;

    for (int pass = 0; pass < 2; ++pass) {
        const float* src = pass ? If : Im;
        const float* gg = pass ? g1k : g1q;
        const float* bb = pass ? b1k : b1q;
        bf16_t* dst = pass ? yln : xln;

        for (int i = tid; i < 96 * 40; i += 256) {
            int c = i / 40, w = i % 40;
            tile[w * 97 + c] = src[(size_t)(b * 96 + c) * 76800 + d * 1920 + h * 40 + w];
        }
        __syncthreads();
        if (tid < 40) {
            float s = 0.f, s2 = 0.f;
            for (int c = 0; c < 96; ++c) {
                float v = tile[tid * 97 + c];
                s += v; s2 += v * v;
            }
            float m = s * (1.f / 96.f);
            float var = s2 * (1.f / 96.f) - m * m;
            mean_s[tid] = m;
            rstd_s[tid] = rsqrtf(var + 1e-5f);
        }
        __syncthreads();
        for (int i = tid; i < 40 * 96; i += 256) {
            int w = i / 96, c = i % 96;
            int tok = tok_index(b, d, h, w);
            float raw = tile[w * 97 + c];
            float v = (raw - mean_s[w]) * rstd_s[w] * gg[c] + bb[c];
            dst[(size_t)tok * 96 + c] = (bf16_t)v;
            if (pass == 0) x2s[(size_t)tok * 96 + c] = raw;   // shortcut
        }
        __syncthreads();
    }
}

// ---------------------------------------------------------------------------
// K2: MFMA projection. WT is [N][96] bf16. N=96 -> qb only.
// N=192 -> n<96 writes kb [t][c]; n>=96 writes vT [win][c][160].
// grid = 2400 (64 tokens/block), 256 threads = 4 waves.
// ---------------------------------------------------------------------------
__global__ __launch_bounds__(256) void k_proj_mfma(
    const bf16_t* __restrict__ X, const bf16_t* __restrict__ WT,
    const float* __restrict__ bias, int N,
    bf16_t* __restrict__ outA, bf16_t* __restrict__ vT)
{
    __shared__ bf16_t xs[64 * 104];
    int tid = threadIdx.x;
    int t0 = blockIdx.x * 64;

    const uint4* xg = (const uint4*)(X + (size_t)t0 * 96);
    uint4* xsv = (uint4*)xs;
    for (int i = tid; i < 768; i += 256) {
        int row = i / 12, c16 = i % 12;
        xsv[row * 13 + c16] = xg[i];
    }
    __syncthreads();

    int w = tid >> 6, l = tid & 63;
    int lm = l & 15, lk = (l >> 4) * 8;
    int m0 = w * 16;
    bf16x8 a[3];
#pragma unroll
    for (int kk = 0; kk < 3; ++kk)
        a[kk] = *(const bf16x8*)(xs + (m0 + lm) * 104 + kk * 32 + lk);

    int trow[4], twin[4], tm[4];
#pragma unroll
    for (int r = 0; r < 4; ++r) {
        int t = t0 + m0 + (l >> 4) * 4 + r;
        trow[r] = t; twin[r] = t / 150; tm[r] = t - twin[r] * 150;
    }

    int ntiles = N >> 4;
    for (int ti = 0; ti < ntiles; ++ti) {
        int n0 = ti * 16;
        f32x4 c = {0.f, 0.f, 0.f, 0.f};
        const bf16_t* wp = WT + (size_t)(n0 + lm) * 96 + lk;
        c = __builtin_amdgcn_mfma_f32_16x16x32_bf16(a[0], *(const bf16x8*)(wp), c, 0, 0, 0);
        c = __builtin_amdgcn_mfma_f32_16x16x32_bf16(a[1], *(const bf16x8*)(wp + 32), c, 0, 0, 0);
        c = __builtin_amdgcn_mfma_f32_16x16x32_bf16(a[2], *(const bf16x8*)(wp + 64), c, 0, 0, 0);
        int n = n0 + lm;
        float bs = bias[n];
        if (n < 96) {
#pragma unroll
            for (int r = 0; r < 4; ++r)
                outA[(size_t)trow[r] * 96 + n] = (bf16_t)(c[r] + bs);
        } else {
            int cc = n - 96;
#pragma unroll
            for (int r = 0; r < 4; ++r)
                vT[((size_t)twin[r] * 96 + cc) * 160 + tm[r]] = (bf16_t)(c[r] + bs);
        }
    }
}

// ---------------------------------------------------------------------------
// K34: MFMA attention, one block (6 waves) per window. K staged in LDS once
// ([160][104] bf16, rows>=150 zeroed); each wave owns row-tiles wv, wv+6.
// P/O round-trip through per-wave LDS scratch [16][164]. V and wproj B-frags
// straight from global (L2-hot). x2 += O@wprojT + bproj (shortcut pre-added).
// LDS: 33280 + 6*5248 = 64768 B -> 2 blocks/CU = 12 waves/CU.
// ---------------------------------------------------------------------------
__global__ __launch_bounds__(384) void k_attn_mfma(
    const bf16_t* __restrict__ qb, const bf16_t* __restrict__ kb,
    const bf16_t* __restrict__ vT, const bf16_t* __restrict__ wpjT,
    const float* __restrict__ bias_mat, const float* __restrict__ bproj,
    float* __restrict__ x2)
{
    __shared__ __align__(16) bf16_t kls[160 * 104];        // 33280 B
    __shared__ __align__(16) bf16_t pls_all[6 * 16 * 164]; // 31488 B
    int win = blockIdx.x;
    int tid = threadIdx.x;
    int wv = tid >> 6, l = tid & 63;
    int lm = l & 15, lq = l >> 4, lk8 = lq * 8;
    size_t wbase = (size_t)win * 150 * 96;
    size_t vbase = (size_t)win * 96 * 160;
    bf16_t* pls = pls_all + wv * 16 * 164;

    // ---- stage K into LDS (coalesced 16B chunks), zero pad rows 150..159 ----
    {
        const uint4* src = (const uint4*)(kb + wbase);   // 150 rows x 12 chunks
        for (int i = tid; i < 1800; i += 384) {
            int row = i / 12, c = i % 12;
            *(uint4*)(kls + row * 104 + c * 8) = src[i];
        }
        uint4 z = {0, 0, 0, 0};
        for (int i = tid; i < 130; i += 384) {           // 10 rows x 13 chunks
            int row = 150 + i / 13, c = i % 13;
            *(uint4*)(kls + row * 104 + c * 8) = z;
        }
    }
    __syncthreads();

    for (int ti = wv; ti < 10; ti += 6) {
        int r0 = ti * 16;

        // ---- S = Q K^T (Q A-frags from global, K B-frags from LDS) ----
        bf16x8 aq[3];
#pragma unroll
        for (int kk = 0; kk < 3; ++kk)
            aq[kk] = *(const bf16x8*)(qb + wbase + (size_t)(r0 + lm) * 96 + kk * 32 + lk8);

        f32x4 s[10];
#pragma unroll
        for (int nt = 0; nt < 10; ++nt) {
            f32x4 acc = {0.f, 0.f, 0.f, 0.f};
            const bf16_t* kp = kls + (nt * 16 + lm) * 104 + lk8;
            acc = __builtin_amdgcn_mfma_f32_16x16x32_bf16(aq[0], *(const bf16x8*)(kp), acc, 0, 0, 0);
            acc = __builtin_amdgcn_mfma_f32_16x16x32_bf16(aq[1], *(const bf16x8*)(kp + 32), acc, 0, 0, 0);
            acc = __builtin_amdgcn_mfma_f32_16x16x32_bf16(aq[2], *(const bf16x8*)(kp + 64), acc, 0, 0, 0);
            s[nt] = acc;
        }

        // ---- softmax (bias+mask folded into bias_mat) ----
#pragma unroll
        for (int r = 0; r < 4; ++r) {
            int grow = r0 + lq * 4 + r;
            float rowmax = -3.0e38f;
#pragma unroll
            for (int nt = 0; nt < 10; ++nt) {
                float bv = bias_mat[grow * 160 + nt * 16 + lm];
                float v = fmaf(s[nt][r], SCALE, bv);
                s[nt][r] = v;
                rowmax = fmaxf(rowmax, v);
            }
            rowmax = fmaxf(rowmax, __shfl_xor(rowmax, 1));
            rowmax = fmaxf(rowmax, __shfl_xor(rowmax, 2));
            rowmax = fmaxf(rowmax, __shfl_xor(rowmax, 4));
            rowmax = fmaxf(rowmax, __shfl_xor(rowmax, 8));
            float ssum = 0.f;
#pragma unroll
            for (int nt = 0; nt < 10; ++nt) {
                float e = __expf(s[nt][r] - rowmax);
                s[nt][r] = e;
                ssum += e;
            }
            ssum += __shfl_xor(ssum, 1);
            ssum += __shfl_xor(ssum, 2);
            ssum += __shfl_xor(ssum, 4);
            ssum += __shfl_xor(ssum, 8);
            float inv = 1.f / ssum;
            int lrow = lq * 4 + r;
#pragma unroll
            for (int nt = 0; nt < 10; ++nt)
                pls[lrow * 164 + nt * 16 + lm] = (bf16_t)(s[nt][r] * inv);
        }
        // wave-private LDS: no barrier needed (lgkmcnt orders within wave)

        // ---- O = P @ V (P A-frags from LDS, V B-frags from global) ----
        f32x4 o[6];
#pragma unroll
        for (int ct = 0; ct < 6; ++ct) o[ct] = (f32x4){0.f, 0.f, 0.f, 0.f};
#pragma unroll
        for (int kf = 0; kf < 5; ++kf) {
            bf16x8 ap = *(const bf16x8*)(pls + lm * 164 + kf * 32 + lk8);
#pragma unroll
            for (int ct = 0; ct < 6; ++ct) {
                const bf16_t* vp = vT + vbase + (size_t)(ct * 16 + lm) * 160 + kf * 32 + lk8;
                o[ct] = __builtin_amdgcn_mfma_f32_16x16x32_bf16(ap, *(const bf16x8*)(vp), o[ct], 0, 0, 0);
            }
        }

        // ---- O -> LDS (A-layout staging), reuse pls as [16][104] ----
#pragma unroll
        for (int ct = 0; ct < 6; ++ct)
#pragma unroll
            for (int r = 0; r < 4; ++r)
                pls[(lq * 4 + r) * 104 + ct * 16 + lm] = (bf16_t)o[ct][r];

        // ---- x2 += O @ wprojT + bproj ----
        bf16x8 ao[3];
#pragma unroll
        for (int kk = 0; kk < 3; ++kk)
            ao[kk] = *(const bf16x8*)(pls + lm * 104 + kk * 32 + lk8);
        f32x4 pj[6];
#pragma unroll
        for (int ct = 0; ct < 6; ++ct) {
            f32x4 acc = {0.f, 0.f, 0.f, 0.f};
            const bf16_t* wp = wpjT + (size_t)(ct * 16 + lm) * 96 + lk8;
            acc = __builtin_amdgcn_mfma_f32_16x16x32_bf16(ao[0], *(const bf16x8*)(wp), acc, 0, 0, 0);
            acc = __builtin_amdgcn_mfma_f32_16x16x32_bf16(ao[1], *(const bf16x8*)(wp + 32), acc, 0, 0, 0);
            acc = __builtin_amdgcn_mfma_f32_16x16x32_bf16(ao[2], *(const bf16x8*)(wp + 64), acc, 0, 0, 0);
            pj[ct] = acc;
        }
#pragma unroll
        for (int r = 0; r < 4; ++r) {
            int gr = r0 + lq * 4 + r;
            if (gr < 150) {
                size_t t = (size_t)win * 150 + gr;
#pragma unroll
                for (int ct = 0; ct < 6; ++ct) {
                    int c = ct * 16 + lm;
                    size_t off = t * 96 + c;
                    x2[off] = x2[off] + pj[ct][r] + bproj[c];
                }
            }
        }
    }
}

// ---------------------------------------------------------------------------
// K5: MFMA MLP. LayerNorm in registers (no fp32 LDS tile): thread owns 1/4
// token (24 ch), 2-hop shuffle for stats, bf16 pack straight into xs.
// LDS = 13312 (xs) + 17408 (hs) = 30720 B -> 5 blocks/CU.
// x3 = x2 + gelu(ln2(x2)@w1+b1)@w2+b2, written bf16 in SPATIAL order for conv.
// grid = 2400 (64 tokens), 256 threads = 4 waves.
// ---------------------------------------------------------------------------
__global__ __launch_bounds__(256, 5) void k_mlp_mfma(
    const float* __restrict__ x2,
    const float* __restrict__ g2, const float* __restrict__ b2,
    const bf16_t* __restrict__ w1T, const float* __restrict__ b1,
    const bf16_t* __restrict__ w2T, const float* __restrict__ b2v,
    bf16_t* __restrict__ xc)
{
    __shared__ __align__(16) bf16_t xs[64 * 104];      // 13312 B
    __shared__ __align__(16) bf16_t hs[4 * 16 * 136];  // 17408 B

    int tid = threadIdx.x;
    int t0 = blockIdx.x * 64;

    // ---- register LayerNorm: thread = (token t, quarter p) ----
    {
        int t = tid >> 2, p = tid & 3;
        float xr[24];
        const float4* xg = (const float4*)(x2 + (size_t)(t0 + t) * 96 + p * 24);
#pragma unroll
        for (int j4 = 0; j4 < 6; ++j4) {
            float4 v = xg[j4];
            xr[j4 * 4 + 0] = v.x; xr[j4 * 4 + 1] = v.y;
            xr[j4 * 4 + 2] = v.z; xr[j4 * 4 + 3] = v.w;
        }
        float s = 0.f, s2 = 0.f;
#pragma unroll
        for (int j = 0; j < 24; ++j) { s += xr[j]; s2 += xr[j] * xr[j]; }
        s += __shfl_xor(s, 1); s += __shfl_xor(s, 2);
        s2 += __shfl_xor(s2, 1); s2 += __shfl_xor(s2, 2);
        float m = s * (1.f / 96.f);
        float var = s2 * (1.f / 96.f) - m * m;
        float rstd = rsqrtf(var + 1e-5f);

        const float4* gg = (const float4*)(g2 + p * 24);
        const float4* bb = (const float4*)(b2 + p * 24);
        bf16_t tmp[24];
#pragma unroll
        for (int j4 = 0; j4 < 6; ++j4) {
            float4 g = gg[j4], bv = bb[j4];
            tmp[j4 * 4 + 0] = (bf16_t)((xr[j4 * 4 + 0] - m) * rstd * g.x + bv.x);
            tmp[j4 * 4 + 1] = (bf16_t)((xr[j4 * 4 + 1] - m) * rstd * g.y + bv.y);
            tmp[j4 * 4 + 2] = (bf16_t)((xr[j4 * 4 + 2] - m) * rstd * g.z + bv.z);
            tmp[j4 * 4 + 3] = (bf16_t)((xr[j4 * 4 + 3] - m) * rstd * g.w + bv.w);
        }
        uint4* dst = (uint4*)(xs + t * 104 + p * 24);   // 48B per quarter, 16B-aligned
        const uint4* src = (const uint4*)tmp;
        dst[0] = src[0]; dst[1] = src[1]; dst[2] = src[2];
    }
    __syncthreads();

    int w = tid >> 6, l = tid & 63;
    int lm = l & 15, lk = (l >> 4) * 8;
    int m0 = w * 16;
    bf16_t* hw = hs + w * 16 * 136;

    bf16x8 a[3];
#pragma unroll
    for (int kk = 0; kk < 3; ++kk)
        a[kk] = *(const bf16x8*)(xs + (m0 + lm) * 104 + kk * 32 + lk);

    f32x4 acc2[6];
#pragma unroll
    for (int i = 0; i < 6; ++i) acc2[i] = (f32x4){0.f, 0.f, 0.f, 0.f};

    for (int cc = 0; cc < 3; ++cc) {
#pragma unroll
        for (int ti = 0; ti < 8; ++ti) {
            int n = cc * 128 + ti * 16 + lm;
            const bf16_t* wp = w1T + (size_t)n * 96 + lk;
            f32x4 c1 = {0.f, 0.f, 0.f, 0.f};
            c1 = __builtin_amdgcn_mfma_f32_16x16x32_bf16(a[0], *(const bf16x8*)(wp), c1, 0, 0, 0);
            c1 = __builtin_amdgcn_mfma_f32_16x16x32_bf16(a[1], *(const bf16x8*)(wp + 32), c1, 0, 0, 0);
            c1 = __builtin_amdgcn_mfma_f32_16x16x32_bf16(a[2], *(const bf16x8*)(wp + 64), c1, 0, 0, 0);
            float bs = b1[n];
#pragma unroll
            for (int r = 0; r < 4; ++r) {
                int row = (l >> 4) * 4 + r;
                hw[row * 136 + ti * 16 + lm] = (bf16_t)gelu_f(c1[r] + bs);
            }
        }
        bf16x8 ha[4];
#pragma unroll
        for (int kk = 0; kk < 4; ++kk)
            ha[kk] = *(const bf16x8*)(hw + lm * 136 + kk * 32 + lk);
#pragma unroll
        for (int ti = 0; ti < 6; ++ti) {
            const bf16_t* wp = w2T + (size_t)(ti * 16 + lm) * 384 + cc * 128 + lk;
#pragma unroll
            for (int kk = 0; kk < 4; ++kk)
                acc2[ti] = __builtin_amdgcn_mfma_f32_16x16x32_bf16(
                    ha[kk], *(const bf16x8*)(wp + kk * 32), acc2[ti], 0, 0, 0);
        }
    }

    // epilogue: residual + bias; write bf16 in spatial order for the conv
    int srow[4];
#pragma unroll
    for (int r = 0; r < 4; ++r) {
        int t = t0 + m0 + (l >> 4) * 4 + r;
        int win = t / 150, nn = t - win * 150;
        int b = win >> 9, d0 = (win >> 6) & 7, h0 = (win >> 3) & 7, w0 = win & 7;
        int wd = nn / 30, rem = nn % 30, wh = rem / 5, ww = rem % 5;
        srow[r] = ((b * 40 + d0 * 5 + wd) * 48 + h0 * 6 + wh) * 40 + w0 * 5 + ww;
    }
#pragma unroll
    for (int ti = 0; ti < 6; ++ti) {
        int n = ti * 16 + lm;
        float bs = b2v[n];
#pragma unroll
        for (int r = 0; r < 4; ++r) {
            int t = t0 + m0 + (l >> 4) * 4 + r;
            size_t o = (size_t)t * 96 + n;
            xc[(size_t)srow[r] * 96 + n] = (bf16_t)(x2[o] + acc2[ti][r] + bs);
        }
    }
}

// ---------------------------------------------------------------------------
// K6: 3x3x3 conv (96 -> 3), zero pad. Input xc: bf16, spatial (b,d,h,w,c).
// Weights cwT[kk][oc][ci] staged in LDS, read as broadcast float4.
// grid = 600, 256 threads (one thread per spatial point, 3 out channels).
// ---------------------------------------------------------------------------
__global__ __launch_bounds__(256) void k_conv(
    const bf16_t* __restrict__ xc, const float* __restrict__ cwT,
    const float* __restrict__ cb, float* __restrict__ out)
{
    __shared__ float wl[7776];   // [kk][oc][ci]
    int tid = threadIdx.x;
    for (int i = tid; i < 7776; i += 256) wl[i] = cwT[i];
    __syncthreads();

    int s = blockIdx.x * 256 + tid;
    int b = s / 76800, r = s % 76800;
    int d = r / 1920, h = (r / 40) % 48, w = r % 40;
    float a0 = 0.f, a1 = 0.f, a2 = 0.f;

    for (int dd = 0; dd < 3; ++dd) {
        int d2 = d + dd - 1;
        if ((unsigned)d2 >= 40u) continue;
        for (int hh = 0; hh < 3; ++hh) {
            int h2 = h + hh - 1;
            if ((unsigned)h2 >= 48u) continue;
            for (int ww = 0; ww < 3; ++ww) {
                int w2 = w + ww - 1;
                if ((unsigned)w2 >= 40u) continue;
                int kk = (dd * 3 + hh) * 3 + ww;
                const bf16x8* xp = (const bf16x8*)
                    (xc + ((size_t)((b * 40 + d2) * 48 + h2) * 40 + w2) * 96);
                const float* wk = wl + kk * 288;
#pragma unroll
                for (int c8 = 0; c8 < 12; ++c8) {
                    bf16x8 xv = xp[c8];
                    float x0 = (float)xv[0], x1 = (float)xv[1];
                    float x2v = (float)xv[2], x3 = (float)xv[3];
                    float x4 = (float)xv[4], x5 = (float)xv[5];
                    float x6 = (float)xv[6], x7 = (float)xv[7];
                    float4 wa0 = *(const float4*)(wk + c8 * 8);
                    float4 wb0 = *(const float4*)(wk + c8 * 8 + 4);
                    float4 wa1 = *(const float4*)(wk + 96 + c8 * 8);
                    float4 wb1 = *(const float4*)(wk + 96 + c8 * 8 + 4);
                    float4 wa2 = *(const float4*)(wk + 192 + c8 * 8);
                    float4 wb2 = *(const float4*)(wk + 192 + c8 * 8 + 4);
                    a0 += x0 * wa0.x + x1 * wa0.y + x2v * wa0.z + x3 * wa0.w
                        + x4 * wb0.x + x5 * wb0.y + x6 * wb0.z + x7 * wb0.w;
                    a1 += x0 * wa1.x + x1 * wa1.y + x2v * wa1.z + x3 * wa1.w
                        + x4 * wb1.x + x5 * wb1.y + x6 * wb1.z + x7 * wb1.w;
                    a2 += x0 * wa2.x + x1 * wa2.y + x2v * wa2.z + x3 * wa2.w
                        + x4 * wb2.x + x5 * wb2.y + x6 * wb2.z + x7 * wb2.w;
                }
            }
        }
    }
    out[(size_t)(b * 3 + 0) * 76800 + r] = a0 + cb[0];
    out[(size_t)(b * 3 + 1) * 76800 + r] = a1 + cb[1];
    out[(size_t)(b * 3 + 2) * 76800 + r] = a2 + cb[2];
}

// ---------------------------------------------------------------------------
extern "C" void kernel_launch(void* const* d_in, const int* in_sizes, int n_in,
                              void* d_out, int out_size, void* d_ws, size_t ws_size,
                              hipStream_t stream)
{
    (void)in_sizes; (void)n_in; (void)out_size;

    const float* Im  = (const float*)d_in[0];
    const float* If  = (const float*)d_in[1];
    const float* g1q = (const float*)d_in[2];
    const float* b1q = (const float*)d_in[3];
    const float* g1k = (const float*)d_in[4];
    const float* b1k = (const float*)d_in[5];
    const float* wq  = (const float*)d_in[6];
    const float* bq  = (const float*)d_in[7];
    const float* wkv = (const float*)d_in[8];
    const float* bkv = (const float*)d_in[9];
    const float* wpj = (const float*)d_in[10];
    const float* bpj = (const float*)d_in[11];
    const float* rb  = (const float*)d_in[12];
    const float* g2  = (const float*)d_in[13];
    const float* b2  = (const float*)d_in[14];
    const float* w1  = (const float*)d_in[15];
    const float* b1  = (const float*)d_in[16];
    const float* w2  = (const float*)d_in[17];
    const float* b2v = (const float*)d_in[18];
    const float* cw  = (const float*)d_in[19];
    const float* cb  = (const float*)d_in[20];
    float* out = (float*)d_out;

    size_t U = (size_t)NTOK * 96;
    if (ws_size < 4 * U * sizeof(float)) return;
    float* ws = (float*)d_ws;
    bf16_t* xlnb = (bf16_t*)ws;                        // U bf16 (-> xc later)
    bf16_t* ylnb = (bf16_t*)(ws + U / 2);              // U bf16
    bf16_t* qb   = (bf16_t*)(ws + U);                  // U bf16
    bf16_t* kb   = (bf16_t*)(ws + 3 * U / 2);          // U bf16
    bf16_t* vT   = (bf16_t*)(ws + 2 * U);              // 1024*96*160 bf16
    float*  wtail = ws + 2 * U + (1024 * 96 * 160) / 2;
    bf16_t* wqT  = (bf16_t*)wtail;                     // 9216
    bf16_t* wkvT = wqT + 9216;                         // 18432
    bf16_t* w1T  = wkvT + 18432;                       // 36864
    bf16_t* w2T  = w1T + 36864;                        // 36864
    bf16_t* wpjT = w2T + 36864;                        // 9216
    float*  bias_mat = (float*)(wpjT + 9216 + 2);      // 25600 fp32
    float*  cwT  = bias_mat + 25600;                   // 7776 fp32
    float*  x2f  = ws + 3 * U;                         // U fp32
    bf16_t* xc   = (bf16_t*)ws;                        // U bf16, spatial order
                                                       // (aliases dead xlnb/yl)

    k_prep_weights<<<144, 256, 0, stream>>>(wq, wkv, w1, w2, wpj, rb, cw,
                                            wqT, wkvT, w1T, w2T, wpjT,
                                            bias_mat, cwT);
    k_ln_transpose<<<3840, 256, 0, stream>>>(Im, If, g1q, b1q, g1k, b1k,
                                             xlnb, ylnb, x2f);
    k_proj_mfma<<<2400, 256, 0, stream>>>(xlnb, wqT, bq, 96, qb, nullptr);
    k_proj_mfma<<<2400, 256, 0, stream>>>(ylnb, wkvT, bkv, 192, kb, vT);
    k_attn_mfma<<<1024, 384, 0, stream>>>(qb, kb, vT, wpjT, bias_mat, bpj, x2f);
    k_mlp_mfma<<<2400, 256, 0, stream>>>(x2f, g2, b2, w1T, b1, w2T, b2v, xc);
    k_conv<<<600, 256, 0, stream>>>(xc, cwT, cb, out);
}

// Round 7
// 700.150 us; speedup vs baseline: 2.8032x; 1.0174x over previous
//
#include <hip/hip_runtime.h>
#include <math.h>

// ---------------------------------------------------------------------------
// Swin-3D cross-attention block. Round 6: k_mlp software pipeline — hidden
// chunk 96, per-wave double-buffered h scratch, hand-unrolled s1/s2 overlap.
// Token order = window-partitioned:
//   win = ((b*8 + d/5)*8 + h/6)*8 + w/5 ; t = ((d%5)*6 + h%6)*5 + w%5
// ---------------------------------------------------------------------------

static constexpr int NTOK = 153600;
static constexpr float SCALE = 0.10206207261596575f; // 96^-0.5

typedef __bf16 bf16_t;
typedef __bf16 bf16x8 __attribute__((ext_vector_type(8)));
typedef float f32x4 __attribute__((ext_vector_type(4)));

__device__ __forceinline__ int tok_index(int b, int d, int h, int w) {
    int d0 = d / 5, wd = d % 5;
    int h0 = h / 6, wh = h % 6;
    int w0 = w / 5, ww = w % 5;
    int win = ((b * 8 + d0) * 8 + h0) * 8 + w0;
    return win * 150 + (wd * 6 + wh) * 5 + ww;
}

__device__ __forceinline__ float gelu_f(float u) {
    float u2 = u * u;
    float arg = u * fmaf(0.0713549f, u2, 1.5957691f);
    float e = __expf(arg);
    float r = __builtin_amdgcn_rcpf(e + 1.f);
    return fmaf(-u, r, u);
}

// ---------------------------------------------------------------------------
// K0: weight convert/transpose bf16 [n][k]; fp32 bias matrix [160][160];
// conv weights re-laid to cwT[kk][oc][ci] (ci-contiguous for float4 reads).
// ---------------------------------------------------------------------------
__global__ __launch_bounds__(256) void k_prep_weights(
    const float* __restrict__ wq, const float* __restrict__ wkv,
    const float* __restrict__ w1, const float* __restrict__ w2,
    const float* __restrict__ wproj, const float* __restrict__ relb,
    const float* __restrict__ cw,
    bf16_t* wqT, bf16_t* wkvT, bf16_t* w1T, bf16_t* w2T, bf16_t* wpjT,
    float* bias_mat, float* cwT)
{
    int i = blockIdx.x * 256 + threadIdx.x;
    if (i < 9216)  wqT[i]  = (bf16_t)wq[(i % 96) * 96 + i / 96];
    if (i < 18432) wkvT[i] = (bf16_t)wkv[(i % 96) * 192 + i / 96];
    if (i < 36864) w1T[i]  = (bf16_t)w1[(i % 96) * 384 + i / 96];
    if (i < 36864) w2T[i]  = (bf16_t)w2[(i % 384) * 96 + i / 384];
    if (i < 9216)  wpjT[i] = (bf16_t)wproj[(i % 96) * 96 + i / 96];
    if (i < 25600) {
        int row = i / 160, col = i % 160;
        float v;
        if (col >= 150) v = -1e30f;
        else if (row >= 150) v = 0.f;
        else {
            int wd1 = row / 30, rh1 = row % 30, wh1 = rh1 / 5, ww1 = rh1 % 5;
            int wd2 = col / 30, rh2 = col % 30, wh2 = rh2 / 5, ww2 = rh2 % 5;
            int idx = (wd1 - wd2 + 4) * 99 + (wh1 - wh2 + 5) * 9 + (ww1 - ww2 + 4);
            v = relb[idx];
        }
        bias_mat[i] = v;
    }
    if (i < 7776) {
        int kk = i / 288, rem = i % 288;
        int oc = rem / 96, ci = rem % 96;
        cwT[i] = cw[oc * 2592 + ci * 27 + kk];
    }
}

// ---------------------------------------------------------------------------
// K1: transpose->token order + LayerNorm (bf16 out) + fp32 Im shortcut to x2.
// grid = 3840, 256 threads.
// ---------------------------------------------------------------------------
__global__ __launch_bounds__(256) void k_ln_transpose(
    const float* __restrict__ Im, const float* __restrict__ If,
    const float* __restrict__ g1q, const float* __restrict__ b1q,
    const float* __restrict__ g1k, const float* __restrict__ b1k,
    bf16_t* __restrict__ xln, bf16_t* __restrict__ yln,
    float* __restrict__ x2s)
{
    __shared__ float tile[40 * 97];
    __shared__ float mean_s[40], rstd_s[40];
    int blk = blockIdx.x;
    int b = blk / (40 * 48);
    int rem = blk % (40 * 48);
    int d = rem / 48, h = rem % 48;
    int tid = threadIdx.x;

    for (int pass = 0; pass < 2; ++pass) {
        const float* src = pass ? If : Im;
        const float* gg = pass ? g1k : g1q;
        const float* bb = pass ? b1k : b1q;
        bf16_t* dst = pass ? yln : xln;

        for (int i = tid; i < 96 * 40; i += 256) {
            int c = i / 40, w = i % 40;
            tile[w * 97 + c] = src[(size_t)(b * 96 + c) * 76800 + d * 1920 + h * 40 + w];
        }
        __syncthreads();
        if (tid < 40) {
            float s = 0.f, s2 = 0.f;
            for (int c = 0; c < 96; ++c) {
                float v = tile[tid * 97 + c];
                s += v; s2 += v * v;
            }
            float m = s * (1.f / 96.f);
            float var = s2 * (1.f / 96.f) - m * m;
            mean_s[tid] = m;
            rstd_s[tid] = rsqrtf(var + 1e-5f);
        }
        __syncthreads();
        for (int i = tid; i < 40 * 96; i += 256) {
            int w = i / 96, c = i % 96;
            int tok = tok_index(b, d, h, w);
            float raw = tile[w * 97 + c];
            float v = (raw - mean_s[w]) * rstd_s[w] * gg[c] + bb[c];
            dst[(size_t)tok * 96 + c] = (bf16_t)v;
            if (pass == 0) x2s[(size_t)tok * 96 + c] = raw;   // shortcut
        }
        __syncthreads();
    }
}

// ---------------------------------------------------------------------------
// K2: MFMA projection. WT is [N][96] bf16. N=96 -> qb only.
// N=192 -> n<96 writes kb [t][c]; n>=96 writes vT [win][c][160].
// grid = 2400 (64 tokens/block), 256 threads = 4 waves.
// ---------------------------------------------------------------------------
__global__ __launch_bounds__(256) void k_proj_mfma(
    const bf16_t* __restrict__ X, const bf16_t* __restrict__ WT,
    const float* __restrict__ bias, int N,
    bf16_t* __restrict__ outA, bf16_t* __restrict__ vT)
{
    __shared__ bf16_t xs[64 * 104];
    int tid = threadIdx.x;
    int t0 = blockIdx.x * 64;

    const uint4* xg = (const uint4*)(X + (size_t)t0 * 96);
    uint4* xsv = (uint4*)xs;
    for (int i = tid; i < 768; i += 256) {
        int row = i / 12, c16 = i % 12;
        xsv[row * 13 + c16] = xg[i];
    }
    __syncthreads();

    int w = tid >> 6, l = tid & 63;
    int lm = l & 15, lk = (l >> 4) * 8;
    int m0 = w * 16;
    bf16x8 a[3];
#pragma unroll
    for (int kk = 0; kk < 3; ++kk)
        a[kk] = *(const bf16x8*)(xs + (m0 + lm) * 104 + kk * 32 + lk);

    int trow[4], twin[4], tm[4];
#pragma unroll
    for (int r = 0; r < 4; ++r) {
        int t = t0 + m0 + (l >> 4) * 4 + r;
        trow[r] = t; twin[r] = t / 150; tm[r] = t - twin[r] * 150;
    }

    int ntiles = N >> 4;
    for (int ti = 0; ti < ntiles; ++ti) {
        int n0 = ti * 16;
        f32x4 c = {0.f, 0.f, 0.f, 0.f};
        const bf16_t* wp = WT + (size_t)(n0 + lm) * 96 + lk;
        c = __builtin_amdgcn_mfma_f32_16x16x32_bf16(a[0], *(const bf16x8*)(wp), c, 0, 0, 0);
        c = __builtin_amdgcn_mfma_f32_16x16x32_bf16(a[1], *(const bf16x8*)(wp + 32), c, 0, 0, 0);
        c = __builtin_amdgcn_mfma_f32_16x16x32_bf16(a[2], *(const bf16x8*)(wp + 64), c, 0, 0, 0);
        int n = n0 + lm;
        float bs = bias[n];
        if (n < 96) {
#pragma unroll
            for (int r = 0; r < 4; ++r)
                outA[(size_t)trow[r] * 96 + n] = (bf16_t)(c[r] + bs);
        } else {
            int cc = n - 96;
#pragma unroll
            for (int r = 0; r < 4; ++r)
                vT[((size_t)twin[r] * 96 + cc) * 160 + tm[r]] = (bf16_t)(c[r] + bs);
        }
    }
}

// ---------------------------------------------------------------------------
// K34: MFMA attention, one block (6 waves) per window. K staged in LDS once
// ([160][104] bf16, rows>=150 zeroed); each wave owns row-tiles wv, wv+6.
// P/O round-trip through per-wave LDS scratch [16][164]. V and wproj B-frags
// straight from global (L2-hot). x2 += O@wprojT + bproj (shortcut pre-added).
// ---------------------------------------------------------------------------
__global__ __launch_bounds__(384) void k_attn_mfma(
    const bf16_t* __restrict__ qb, const bf16_t* __restrict__ kb,
    const bf16_t* __restrict__ vT, const bf16_t* __restrict__ wpjT,
    const float* __restrict__ bias_mat, const float* __restrict__ bproj,
    float* __restrict__ x2)
{
    __shared__ __align__(16) bf16_t kls[160 * 104];        // 33280 B
    __shared__ __align__(16) bf16_t pls_all[6 * 16 * 164]; // 31488 B
    int win = blockIdx.x;
    int tid = threadIdx.x;
    int wv = tid >> 6, l = tid & 63;
    int lm = l & 15, lq = l >> 4, lk8 = lq * 8;
    size_t wbase = (size_t)win * 150 * 96;
    size_t vbase = (size_t)win * 96 * 160;
    bf16_t* pls = pls_all + wv * 16 * 164;

    // ---- stage K into LDS (coalesced 16B chunks), zero pad rows 150..159 ----
    {
        const uint4* src = (const uint4*)(kb + wbase);   // 150 rows x 12 chunks
        for (int i = tid; i < 1800; i += 384) {
            int row = i / 12, c = i % 12;
            *(uint4*)(kls + row * 104 + c * 8) = src[i];
        }
        uint4 z = {0, 0, 0, 0};
        for (int i = tid; i < 130; i += 384) {           // 10 rows x 13 chunks
            int row = 150 + i / 13, c = i % 13;
            *(uint4*)(kls + row * 104 + c * 8) = z;
        }
    }
    __syncthreads();

    for (int ti = wv; ti < 10; ti += 6) {
        int r0 = ti * 16;

        // ---- S = Q K^T (Q A-frags from global, K B-frags from LDS) ----
        bf16x8 aq[3];
#pragma unroll
        for (int kk = 0; kk < 3; ++kk)
            aq[kk] = *(const bf16x8*)(qb + wbase + (size_t)(r0 + lm) * 96 + kk * 32 + lk8);

        f32x4 s[10];
#pragma unroll
        for (int nt = 0; nt < 10; ++nt) {
            f32x4 acc = {0.f, 0.f, 0.f, 0.f};
            const bf16_t* kp = kls + (nt * 16 + lm) * 104 + lk8;
            acc = __builtin_amdgcn_mfma_f32_16x16x32_bf16(aq[0], *(const bf16x8*)(kp), acc, 0, 0, 0);
            acc = __builtin_amdgcn_mfma_f32_16x16x32_bf16(aq[1], *(const bf16x8*)(kp + 32), acc, 0, 0, 0);
            acc = __builtin_amdgcn_mfma_f32_16x16x32_bf16(aq[2], *(const bf16x8*)(kp + 64), acc, 0, 0, 0);
            s[nt] = acc;
        }

        // ---- softmax (bias+mask folded into bias_mat) ----
#pragma unroll
        for (int r = 0; r < 4; ++r) {
            int grow = r0 + lq * 4 + r;
            float rowmax = -3.0e38f;
#pragma unroll
            for (int nt = 0; nt < 10; ++nt) {
                float bv = bias_mat[grow * 160 + nt * 16 + lm];
                float v = fmaf(s[nt][r], SCALE, bv);
                s[nt][r] = v;
                rowmax = fmaxf(rowmax, v);
            }
            rowmax = fmaxf(rowmax, __shfl_xor(rowmax, 1));
            rowmax = fmaxf(rowmax, __shfl_xor(rowmax, 2));
            rowmax = fmaxf(rowmax, __shfl_xor(rowmax, 4));
            rowmax = fmaxf(rowmax, __shfl_xor(rowmax, 8));
            float ssum = 0.f;
#pragma unroll
            for (int nt = 0; nt < 10; ++nt) {
                float e = __expf(s[nt][r] - rowmax);
                s[nt][r] = e;
                ssum += e;
            }
            ssum += __shfl_xor(ssum, 1);
            ssum += __shfl_xor(ssum, 2);
            ssum += __shfl_xor(ssum, 4);
            ssum += __shfl_xor(ssum, 8);
            float inv = 1.f / ssum;
            int lrow = lq * 4 + r;
#pragma unroll
            for (int nt = 0; nt < 10; ++nt)
                pls[lrow * 164 + nt * 16 + lm] = (bf16_t)(s[nt][r] * inv);
        }
        // wave-private LDS: no barrier needed (lgkmcnt orders within wave)

        // ---- O = P @ V (P A-frags from LDS, V B-frags from global) ----
        f32x4 o[6];
#pragma unroll
        for (int ct = 0; ct < 6; ++ct) o[ct] = (f32x4){0.f, 0.f, 0.f, 0.f};
#pragma unroll
        for (int kf = 0; kf < 5; ++kf) {
            bf16x8 ap = *(const bf16x8*)(pls + lm * 164 + kf * 32 + lk8);
#pragma unroll
            for (int ct = 0; ct < 6; ++ct) {
                const bf16_t* vp = vT + vbase + (size_t)(ct * 16 + lm) * 160 + kf * 32 + lk8;
                o[ct] = __builtin_amdgcn_mfma_f32_16x16x32_bf16(ap, *(const bf16x8*)(vp), o[ct], 0, 0, 0);
            }
        }

        // ---- O -> LDS (A-layout staging), reuse pls as [16][104] ----
#pragma unroll
        for (int ct = 0; ct < 6; ++ct)
#pragma unroll
            for (int r = 0; r < 4; ++r)
                pls[(lq * 4 + r) * 104 + ct * 16 + lm] = (bf16_t)o[ct][r];

        // ---- x2 += O @ wprojT + bproj ----
        bf16x8 ao[3];
#pragma unroll
        for (int kk = 0; kk < 3; ++kk)
            ao[kk] = *(const bf16x8*)(pls + lm * 104 + kk * 32 + lk8);
        f32x4 pj[6];
#pragma unroll
        for (int ct = 0; ct < 6; ++ct) {
            f32x4 acc = {0.f, 0.f, 0.f, 0.f};
            const bf16_t* wp = wpjT + (size_t)(ct * 16 + lm) * 96 + lk8;
            acc = __builtin_amdgcn_mfma_f32_16x16x32_bf16(ao[0], *(const bf16x8*)(wp), acc, 0, 0, 0);
            acc = __builtin_amdgcn_mfma_f32_16x16x32_bf16(ao[1], *(const bf16x8*)(wp + 32), acc, 0, 0, 0);
            acc = __builtin_amdgcn_mfma_f32_16x16x32_bf16(ao[2], *(const bf16x8*)(wp + 64), acc, 0, 0, 0);
            pj[ct] = acc;
        }
#pragma unroll
        for (int r = 0; r < 4; ++r) {
            int gr = r0 + lq * 4 + r;
            if (gr < 150) {
                size_t t = (size_t)win * 150 + gr;
#pragma unroll
                for (int ct = 0; ct < 6; ++ct) {
                    int c = ct * 16 + lm;
                    size_t off = t * 96 + c;
                    x2[off] = x2[off] + pj[ct][r] + bproj[c];
                }
            }
        }
    }
}

// ---------------------------------------------------------------------------
// K5: MFMA MLP, software-pipelined. LN in registers; hidden in 4 chunks of 96
// with per-wave DOUBLE-BUFFERED h scratch so stage1(cc+1) overlaps stage2(cc).
// LDS = 13312 (xs) + 4*2*3328 (hs dbuf) = 39936 B -> 4 blocks/CU.
// x3 = x2 + gelu(ln2(x2)@w1+b1)@w2+b2, written bf16 in SPATIAL order for conv.
// grid = 2400 (64 tokens), 256 threads = 4 waves.
// ---------------------------------------------------------------------------
__global__ __launch_bounds__(256, 4) void k_mlp_mfma(
    const float* __restrict__ x2,
    const float* __restrict__ g2, const float* __restrict__ b2,
    const bf16_t* __restrict__ w1T, const float* __restrict__ b1,
    const bf16_t* __restrict__ w2T, const float* __restrict__ b2v,
    bf16_t* __restrict__ xc)
{
    __shared__ __align__(16) bf16_t xs[64 * 104];          // 13312 B
    __shared__ __align__(16) bf16_t hs[4 * 2 * 16 * 104];  // 26624 B

    int tid = threadIdx.x;
    int t0 = blockIdx.x * 64;

    // ---- register LayerNorm: thread = (token t, quarter p) ----
    {
        int t = tid >> 2, p = tid & 3;
        float xr[24];
        const float4* xg = (const float4*)(x2 + (size_t)(t0 + t) * 96 + p * 24);
#pragma unroll
        for (int j4 = 0; j4 < 6; ++j4) {
            float4 v = xg[j4];
            xr[j4 * 4 + 0] = v.x; xr[j4 * 4 + 1] = v.y;
            xr[j4 * 4 + 2] = v.z; xr[j4 * 4 + 3] = v.w;
        }
        float s = 0.f, s2 = 0.f;
#pragma unroll
        for (int j = 0; j < 24; ++j) { s += xr[j]; s2 += xr[j] * xr[j]; }
        s += __shfl_xor(s, 1); s += __shfl_xor(s, 2);
        s2 += __shfl_xor(s2, 1); s2 += __shfl_xor(s2, 2);
        float m = s * (1.f / 96.f);
        float var = s2 * (1.f / 96.f) - m * m;
        float rstd = rsqrtf(var + 1e-5f);

        const float4* gg = (const float4*)(g2 + p * 24);
        const float4* bb = (const float4*)(b2 + p * 24);
        bf16_t tmp[24];
#pragma unroll
        for (int j4 = 0; j4 < 6; ++j4) {
            float4 g = gg[j4], bv = bb[j4];
            tmp[j4 * 4 + 0] = (bf16_t)((xr[j4 * 4 + 0] - m) * rstd * g.x + bv.x);
            tmp[j4 * 4 + 1] = (bf16_t)((xr[j4 * 4 + 1] - m) * rstd * g.y + bv.y);
            tmp[j4 * 4 + 2] = (bf16_t)((xr[j4 * 4 + 2] - m) * rstd * g.z + bv.z);
            tmp[j4 * 4 + 3] = (bf16_t)((xr[j4 * 4 + 3] - m) * rstd * g.w + bv.w);
        }
        uint4* dst = (uint4*)(xs + t * 104 + p * 24);   // 48B per quarter
        const uint4* src = (const uint4*)tmp;
        dst[0] = src[0]; dst[1] = src[1]; dst[2] = src[2];
    }
    __syncthreads();

    int w = tid >> 6, l = tid & 63;
    int lm = l & 15, lk = (l >> 4) * 8;
    int m0 = w * 16;
    bf16_t* hw0 = hs + w * 2 * 16 * 104;   // buffer 0
    bf16_t* hw1 = hw0 + 16 * 104;          // buffer 1

    bf16x8 a[3];
#pragma unroll
    for (int kk = 0; kk < 3; ++kk)
        a[kk] = *(const bf16x8*)(xs + (m0 + lm) * 104 + kk * 32 + lk);

    // stage1 of chunk cc into given buffer: h = gelu(xs @ w1_chunk + b1)
    auto s1 = [&](int cc, bf16_t* buf) {
#pragma unroll
        for (int ti = 0; ti < 6; ++ti) {
            int n = cc * 96 + ti * 16 + lm;
            const bf16_t* wp = w1T + (size_t)n * 96 + lk;
            f32x4 c1 = {0.f, 0.f, 0.f, 0.f};
            c1 = __builtin_amdgcn_mfma_f32_16x16x32_bf16(a[0], *(const bf16x8*)(wp), c1, 0, 0, 0);
            c1 = __builtin_amdgcn_mfma_f32_16x16x32_bf16(a[1], *(const bf16x8*)(wp + 32), c1, 0, 0, 0);
            c1 = __builtin_amdgcn_mfma_f32_16x16x32_bf16(a[2], *(const bf16x8*)(wp + 64), c1, 0, 0, 0);
            float bs = b1[n];
#pragma unroll
            for (int r = 0; r < 4; ++r) {
                int row = (l >> 4) * 4 + r;
                buf[row * 104 + ti * 16 + lm] = (bf16_t)gelu_f(c1[r] + bs);
            }
        }
    };

    f32x4 acc2[6];
#pragma unroll
    for (int i = 0; i < 6; ++i) acc2[i] = (f32x4){0.f, 0.f, 0.f, 0.f};

    bf16x8 ha[3];
    // ---- software pipeline: s1(0); rd(0); { s1(cc+1) | s2(cc) | rd(cc+1) } --
    s1(0, hw0);
#pragma unroll
    for (int kk = 0; kk < 3; ++kk)
        ha[kk] = *(const bf16x8*)(hw0 + lm * 104 + kk * 32 + lk);

#pragma unroll
    for (int cc = 0; cc < 4; ++cc) {
        bf16_t* nbuf = (cc & 1) ? hw0 : hw1;
        if (cc < 3) s1(cc + 1, nbuf);          // independent of ha -> overlaps
        // stage2: acc2 += h_chunk @ w2_chunk
#pragma unroll
        for (int ti = 0; ti < 6; ++ti) {
            const bf16_t* wp = w2T + (size_t)(ti * 16 + lm) * 384 + cc * 96 + lk;
#pragma unroll
            for (int kk = 0; kk < 3; ++kk)
                acc2[ti] = __builtin_amdgcn_mfma_f32_16x16x32_bf16(
                    ha[kk], *(const bf16x8*)(wp + kk * 32), acc2[ti], 0, 0, 0);
        }
        if (cc < 3) {
#pragma unroll
            for (int kk = 0; kk < 3; ++kk)
                ha[kk] = *(const bf16x8*)(nbuf + lm * 104 + kk * 32 + lk);
        }
    }

    // epilogue: residual + bias; write bf16 in spatial order for the conv
    int srow[4];
#pragma unroll
    for (int r = 0; r < 4; ++r) {
        int t = t0 + m0 + (l >> 4) * 4 + r;
        int win = t / 150, nn = t - win * 150;
        int b = win >> 9, d0 = (win >> 6) & 7, h0 = (win >> 3) & 7, w0 = win & 7;
        int wd = nn / 30, rem = nn % 30, wh = rem / 5, ww = rem % 5;
        srow[r] = ((b * 40 + d0 * 5 + wd) * 48 + h0 * 6 + wh) * 40 + w0 * 5 + ww;
    }
#pragma unroll
    for (int ti = 0; ti < 6; ++ti) {
        int n = ti * 16 + lm;
        float bs = b2v[n];
#pragma unroll
        for (int r = 0; r < 4; ++r) {
            int t = t0 + m0 + (l >> 4) * 4 + r;
            size_t o = (size_t)t * 96 + n;
            xc[(size_t)srow[r] * 96 + n] = (bf16_t)(x2[o] + acc2[ti][r] + bs);
        }
    }
}

// ---------------------------------------------------------------------------
// K6: 3x3x3 conv (96 -> 3), zero pad. Input xc: bf16, spatial (b,d,h,w,c).
// Weights cwT[kk][oc][ci] staged in LDS, read as broadcast float4.
// grid = 600, 256 threads (one thread per spatial point, 3 out channels).
// ---------------------------------------------------------------------------
__global__ __launch_bounds__(256) void k_conv(
    const bf16_t* __restrict__ xc, const float* __restrict__ cwT,
    const float* __restrict__ cb, float* __restrict__ out)
{
    __shared__ float wl[7776];   // [kk][oc][ci]
    int tid = threadIdx.x;
    for (int i = tid; i < 7776; i += 256) wl[i] = cwT[i];
    __syncthreads();

    int s = blockIdx.x * 256 + tid;
    int b = s / 76800, r = s % 76800;
    int d = r / 1920, h = (r / 40) % 48, w = r % 40;
    float a0 = 0.f, a1 = 0.f, a2 = 0.f;

    for (int dd = 0; dd < 3; ++dd) {
        int d2 = d + dd - 1;
        if ((unsigned)d2 >= 40u) continue;
        for (int hh = 0; hh < 3; ++hh) {
            int h2 = h + hh - 1;
            if ((unsigned)h2 >= 48u) continue;
            for (int ww = 0; ww < 3; ++ww) {
                int w2 = w + ww - 1;
                if ((unsigned)w2 >= 40u) continue;
                int kk = (dd * 3 + hh) * 3 + ww;
                const bf16x8* xp = (const bf16x8*)
                    (xc + ((size_t)((b * 40 + d2) * 48 + h2) * 40 + w2) * 96);
                const float* wk = wl + kk * 288;
#pragma unroll
                for (int c8 = 0; c8 < 12; ++c8) {
                    bf16x8 xv = xp[c8];
                    float x0 = (float)xv[0], x1 = (float)xv[1];
                    float x2v = (float)xv[2], x3 = (float)xv[3];
                    float x4 = (float)xv[4], x5 = (float)xv[5];
                    float x6 = (float)xv[6], x7 = (float)xv[7];
                    float4 wa0 = *(const float4*)(wk + c8 * 8);
                    float4 wb0 = *(const float4*)(wk + c8 * 8 + 4);
                    float4 wa1 = *(const float4*)(wk + 96 + c8 * 8);
                    float4 wb1 = *(const float4*)(wk + 96 + c8 * 8 + 4);
                    float4 wa2 = *(const float4*)(wk + 192 + c8 * 8);
                    float4 wb2 = *(const float4*)(wk + 192 + c8 * 8 + 4);
                    a0 += x0 * wa0.x + x1 * wa0.y + x2v * wa0.z + x3 * wa0.w
                        + x4 * wb0.x + x5 * wb0.y + x6 * wb0.z + x7 * wb0.w;
                    a1 += x0 * wa1.x + x1 * wa1.y + x2v * wa1.z + x3 * wa1.w
                        + x4 * wb1.x + x5 * wb1.y + x6 * wb1.z + x7 * wb1.w;
                    a2 += x0 * wa2.x + x1 * wa2.y + x2v * wa2.z + x3 * wa2.w
                        + x4 * wb2.x + x5 * wb2.y + x6 * wb2.z + x7 * wb2.w;
                }
            }
        }
    }
    out[(size_t)(b * 3 + 0) * 76800 + r] = a0 + cb[0];
    out[(size_t)(b * 3 + 1) * 76800 + r] = a1 + cb[1];
    out[(size_t)(b * 3 + 2) * 76800 + r] = a2 + cb[2];
}

// ---------------------------------------------------------------------------
extern "C" void kernel_launch(void* const* d_in, const int* in_sizes, int n_in,
                              void* d_out, int out_size, void* d_ws, size_t ws_size,
                              hipStream_t stream)
{
    (void)in_sizes; (void)n_in; (void)out_size;

    const float* Im  = (const float*)d_in[0];
    const float* If  = (const float*)d_in[1];
    const float* g1q = (const float*)d_in[2];
    const float* b1q = (const float*)d_in[3];
    const float* g1k = (const float*)d_in[4];
    const float* b1k = (const float*)d_in[5];
    const float* wq  = (const float*)d_in[6];
    const float* bq  = (const float*)d_in[7];
    const float* wkv = (const float*)d_in[8];
    const float* bkv = (const float*)d_in[9];
    const float* wpj = (const float*)d_in[10];
    const float* bpj = (const float*)d_in[11];
    const float* rb  = (const float*)d_in[12];
    const float* g2  = (const float*)d_in[13];
    const float* b2  = (const float*)d_in[14];
    const float* w1  = (const float*)d_in[15];
    const float* b1  = (const float*)d_in[16];
    const float* w2  = (const float*)d_in[17];
    const float* b2v = (const float*)d_in[18];
    const float* cw  = (const float*)d_in[19];
    const float* cb  = (const float*)d_in[20];
    float* out = (float*)d_out;

    size_t U = (size_t)NTOK * 96;
    if (ws_size < 4 * U * sizeof(float)) return;
    float* ws = (float*)d_ws;
    bf16_t* xlnb = (bf16_t*)ws;                        // U bf16 (-> xc later)
    bf16_t* ylnb = (bf16_t*)(ws + U / 2);              // U bf16
    bf16_t* qb   = (bf16_t*)(ws + U);                  // U bf16
    bf16_t* kb   = (bf16_t*)(ws + 3 * U / 2);          // U bf16
    bf16_t* vT   = (bf16_t*)(ws + 2 * U);              // 1024*96*160 bf16
    float*  wtail = ws + 2 * U + (1024 * 96 * 160) / 2;
    bf16_t* wqT  = (bf16_t*)wtail;                     // 9216
    bf16_t* wkvT = wqT + 9216;                         // 18432
    bf16_t* w1T  = wkvT + 18432;                       // 36864
    bf16_t* w2T  = w1T + 36864;                        // 36864
    bf16_t* wpjT = w2T + 36864;                        // 9216
    float*  bias_mat = (float*)(wpjT + 9216 + 2);      // 25600 fp32
    float*  cwT  = bias_mat + 25600;                   // 7776 fp32
    float*  x2f  = ws + 3 * U;                         // U fp32
    bf16_t* xc   = (bf16_t*)ws;                        // U bf16, spatial order

    k_prep_weights<<<144, 256, 0, stream>>>(wq, wkv, w1, w2, wpj, rb, cw,
                                            wqT, wkvT, w1T, w2T, wpjT,
                                            bias_mat, cwT);
    k_ln_transpose<<<3840, 256, 0, stream>>>(Im, If, g1q, b1q, g1k, b1k,
                                             xlnb, ylnb, x2f);
    k_proj_mfma<<<2400, 256, 0, stream>>>(xlnb, wqT, bq, 96, qb, nullptr);
    k_proj_mfma<<<2400, 256, 0, stream>>>(ylnb, wkvT, bkv, 192, kb, vT);
    k_attn_mfma<<<1024, 384, 0, stream>>>(qb, kb, vT, wpjT, bias_mat, bpj, x2f);
    k_mlp_mfma<<<2400, 256, 0, stream>>>(x2f, g2, b2, w1T, b1, w2T, b2v, xc);
    k_conv<<<600, 256, 0, stream>>>(xc, cwT, cb, out);
}